// Round 6
// baseline (304.402 us; speedup 1.0000x reference)
//
#include <hip/hip_runtime.h>
#include <hip/hip_bf16.h>
#include <math.h>

#define NN 20000
#define NE 320000
#define DD 256
#define NH 8
#define KK 32
#define NR 5
#define NC 16
#define NB2 391   // ceil(NN*NR/256)
#define NPAD 20096  // perm-padded row count (boff 32-aligned, 3 types)

typedef unsigned short u16;
typedef unsigned int u32;
typedef __attribute__((ext_vector_type(8))) short bf16x8;
typedef __attribute__((ext_vector_type(4))) float f32x4;

__device__ __forceinline__ float bf2f(u16 v){ return __uint_as_float(((u32)v)<<16); }
__device__ __forceinline__ u16 f2bf(float f){
  u32 u = __float_as_uint(f);
  return (u16)((u + 0x7FFFu + ((u>>16)&1u)) >> 16);
}
// OCP e4m3fn software encode (RNE). |f| << 448 here (K projections ~ N(0,1)).
__device__ __forceinline__ unsigned char f2fp8(float f){
  u32 b = __float_as_uint(f * 0x1.0p-120f);   // e4m3 exp/mant now at bits 26..20
  u32 s = (b >> 24) & 0x80u;
  u32 m = b & 0x7fffffffu;
  u32 r = m + 0x7FFFFu + ((m >> 20) & 1u);    // RNE at bit 20
  return (unsigned char)(s | ((r >> 20) & 0x7fu));
}
// decode (value scaled by 2^-120; the 2^120 is pre-folded into q registers)
#define FP8D(t) __uint_as_float((((t)&0x80u)<<24) | (((t)&0x7fu)<<20))

struct u96 { u32 x, y, z; };   // 12B, align 4 (dwordx3-friendly)

// ---------------- pre1: nb_count + deg + perm=-1 init (independent block ranges) --------
__global__ void k_pre1(const int* __restrict__ ntype, const int* __restrict__ ei,
                       const int* __restrict__ etype, int* __restrict__ cnt,
                       int* __restrict__ off2, int* __restrict__ perm){
  int b = blockIdx.x;
  if(b < 79){
    int n = b*256 + threadIdx.x;
    int t = (n < NN) ? ntype[n] : -1;
    int lane = threadIdx.x & 63;
    #pragma unroll
    for(int tt=0; tt<3; tt++){
      unsigned long long mask = __ballot(t == tt);
      int leader = __ffsll((long long)mask) - 1;
      if(lane == leader) atomicAdd(&cnt[tt], __popcll(mask));
    }
  } else if(b < 1329){
    int e = (b-79)*256 + threadIdx.x;
    if(e < NE) atomicAdd(&off2[ei[NE + e]*NR + etype[e]], 1);
  } else {
    int i = (b-1329)*256 + threadIdx.x;
    if(i < NPAD) perm[i] = -1;
  }
}

// ---------------- pre2: scan1 (block-local exclusive scan) + nb_off (extra block) --------
__global__ __launch_bounds__(256) void k_pre2(int* __restrict__ off2, int* __restrict__ bsum,
                                              const int* __restrict__ cnt, int* __restrict__ boff){
  if(blockIdx.x == NB2){
    if(threadIdx.x == 0){
      int a = (cnt[0]+31)&~31;
      int bb = (cnt[1]+31)&~31;
      boff[0]=0; boff[1]=a; boff[2]=a+bb;
    }
    return;
  }
  __shared__ int sh[256];
  int t = threadIdx.x;
  int i = blockIdx.x*256 + t;
  int v = (i < NN*NR) ? off2[i] : 0;
  sh[t] = v;
  __syncthreads();
  for(int off=1; off<256; off<<=1){
    int val = (t >= off) ? sh[t-off] : 0;
    __syncthreads();
    sh[t] += val;
    __syncthreads();
  }
  if(i < NN*NR) off2[i] = sh[t] - v;          // exclusive within block
  if(t == 255) bsum[blockIdx.x] = sh[255];    // block total
}
__global__ __launch_bounds__(512) void k_scan2(int* __restrict__ bsum, int* __restrict__ off2){
  __shared__ int sh[512];
  int t = threadIdx.x;
  int v = (t < NB2) ? bsum[t] : 0;
  sh[t] = v;
  __syncthreads();
  for(int off=1; off<512; off<<=1){
    int val = (t >= off) ? sh[t-off] : 0;
    __syncthreads();
    sh[t] += val;
    __syncthreads();
  }
  if(t < NB2) bsum[t] = sh[t] - v;            // exclusive block offsets
  if(t == 511) off2[NN*NR] = sh[511];         // grand total
}
// ---------------- pre3: scan3 + nb_scatter (+ inverse perm pos2) ----------------
__global__ void k_pre3(int* __restrict__ off2, const int* __restrict__ bsum,
                       const int* __restrict__ ntype, const int* __restrict__ boff,
                       int* __restrict__ bcur, int* __restrict__ perm,
                       int* __restrict__ pos2){
  int b = blockIdx.x;
  if(b < NB2){
    int i = b*256 + threadIdx.x;
    if(i < NN*NR) off2[i] += bsum[b];
  } else {
    int n = (b-NB2)*256 + threadIdx.x;
    int t = (n < NN) ? ntype[n] : -1;
    int lane = threadIdx.x & 63;
    #pragma unroll
    for(int tt=0; tt<3; tt++){
      unsigned long long mask = __ballot(t == tt);
      if(t == tt){
        int rank = __popcll(mask & ((1ull<<lane)-1ull));
        int leader = __ffsll((long long)mask) - 1;
        int base = 0;
        if(lane == leader) base = atomicAdd(&bcur[tt], __popcll(mask));
        base = __shfl(base, leader);
        int p = boff[tt] + base + rank;
        perm[p] = n;
        pos2[n] = p;               // inverse perm: KVn/Qn/QA/aggrV all perm-ordered
      }
    }
  }
}

// ---------------- work1: escatter + castx + castw + castsmall (independent ranges) ------
// escatter stores PERM POSITIONS of src (pos2[src]) so KVn can be perm-ordered.
__global__ __launch_bounds__(256) void k_work1(
    const int* __restrict__ ei, const int* __restrict__ etype,
    int* __restrict__ off2, int* __restrict__ packed,
    const int* __restrict__ pos2,
    const float* __restrict__ x, u16* __restrict__ xb,
    const float* __restrict__ Wk, const float* __restrict__ Wq,
    const float* __restrict__ Wv, const float* __restrict__ Wa,
    u16* __restrict__ Wtk, u16* __restrict__ Wtq,
    u16* __restrict__ Wtv, u16* __restrict__ Wta,
    const float* __restrict__ rmsg, const float* __restrict__ ratt,
    const float* __restrict__ prior, const float* __restrict__ Wo,
    u16* __restrict__ Mtm, u16* __restrict__ Atb, u16* __restrict__ Wot)
{
  __shared__ float tile[32][33];
  int b = blockIdx.x;
  if(b < 1250){
    int e = b*256 + threadIdx.x;
    if(e < NE){
      int pos = atomicAdd(&off2[ei[NE+e]*NR + etype[e]], 1);
      packed[pos] = pos2[ei[e]];
    }
  } else if(b < 3750){
    int i = (b-1250)*256 + threadIdx.x;     // castx: 8 floats per thread
    float4 v0 = ((const float4*)x)[i*2+0];
    float4 v1 = ((const float4*)x)[i*2+1];
    uint4 o;
    o.x = (u32)f2bf(v0.x) | ((u32)f2bf(v0.y)<<16);
    o.y = (u32)f2bf(v0.z) | ((u32)f2bf(v0.w)<<16);
    o.z = (u32)f2bf(v1.x) | ((u32)f2bf(v1.y)<<16);
    o.w = (u32)f2bf(v1.z) | ((u32)f2bf(v1.w)<<16);
    ((uint4*)xb)[i] = o;
  } else if(b < 4518){
    int bp = b - 3750;                      // castw: 768 tiles = 8 x 8 x 12
    int bx = bp & 7, by = (bp>>3) & 7, z = bp >> 6;
    int tensor = z/3, t = z%3;
    const float* W = (tensor==0) ? Wk : (tensor==1) ? Wq : (tensor==2) ? Wv : Wa;
    u16* O = (tensor==0) ? Wtk : (tensor==1) ? Wtq : (tensor==2) ? Wtv : Wta;
    int i0 = bx*32, j0 = by*32;
    int rr = threadIdx.x>>5, cc = threadIdx.x&31;
    #pragma unroll
    for(int p=0;p<4;p++)
      tile[rr+p*8][cc] = W[t*65536 + (i0+rr+p*8)*256 + j0+cc];
    __syncthreads();
    #pragma unroll
    for(int p=0;p<4;p++)
      O[t*65536 + (j0+rr+p*8)*256 + i0+cc] = f2bf(tile[cc][rr+p*8]);
  } else {
    int bp = b - 4518;                      // castsmall: 336 blocks
    if(bp < 160){
      int idx = bp*256 + threadIdx.x;       // rel_msg transpose: [r,h,k,l] -> [r,h,l,k]
      int l = idx & 31, k = (idx >> 5) & 31, rh = idx >> 10;
      Mtm[(rh*32 + l)*32 + k] = f2bf(rmsg[idx]);
    } else if(bp < 320){
      int idx = (bp-160)*256 + threadIdx.x; // rel_att cast w/ prior/sqrtK folded
      int rh = idx >> 10;
      float scale = prior[rh] * 0.17677669529663687f;  // 1/sqrt(32)
      Atb[idx] = f2bf(ratt[idx] * scale);
    } else {
      int idx = (bp-320)*256 + threadIdx.x; // W_out transpose: [k,c] -> [c,k]
      int c = idx & 15, k = idx >> 4;
      Wot[c*DD + k] = f2bf(Wo[k*NC + c]);
    }
  }
}

// ---------------- FUSED typed K/Q/V projections --------
// KVn rows now 768B: per 4-dim group g: [K 4x fp8e4m3][V 4x bf16] at byte g*12.
// K fp8 cuts k_edge's gathered row from 1KB to 768B (k_edge is delivered-bytes-bound).
#define XSP 264   // padded row (u16) for x-tile / Q stages
#define KSP 784   // padded row (bytes) for KV stage (768 + 16)
__global__ __launch_bounds__(256) void k_projqa(
    const u16* __restrict__ xb, const int* __restrict__ perm, const int* __restrict__ boff,
    const u16* __restrict__ Wtk, const u16* __restrict__ Wtq, const u16* __restrict__ Wtv,
    const float* __restrict__ bk, const float* __restrict__ bq, const float* __restrict__ bv,
    unsigned char* __restrict__ KVn, u16* __restrict__ Qn)
{
  __shared__ unsigned char smemb[32*KSP];   // x-tile (u16 view) -> KV-stage (bytes) -> Q-stage
  __shared__ int gids[32];
  u16* smem = (u16*)smemb;
  int tid = threadIdx.x;
  int ts = (blockIdx.x >> 1)*32;
  int cb = (blockIdx.x & 1)*128;          // column base for this block
  int t = (ts >= boff[2]) ? 2 : (ts >= boff[1]) ? 1 : 0;   // boff 32-aligned
  if(tid < 32) gids[tid] = perm[ts + tid];
  __syncthreads();
  #pragma unroll
  for(int it=0; it<4; it++){
    int q = tid + it*256;
    int row = q >> 5, c = q & 31;
    int g = gids[row];
    uint4 v = make_uint4(0,0,0,0);
    if(g >= 0) v = ((const uint4*)(xb + (size_t)g*DD))[c];
    ((uint4*)(smem + row*XSP))[c] = v;
  }
  __syncthreads();
  int lane = tid & 63;
  int w = tid >> 6;
  int quad = lane >> 4;
  int l16 = lane & 15;
  f32x4 accK[2][2], accQ[2][2], accV[2][2];   // [mt][nt]
  #pragma unroll
  for(int mt=0;mt<2;mt++)
    #pragma unroll
    for(int nt=0;nt<2;nt++){
      accK[mt][nt]=(f32x4)(0.f); accQ[mt][nt]=(f32x4)(0.f); accV[mt][nt]=(f32x4)(0.f);
    }
  const u16* wkp = Wtk + (size_t)t*65536;
  const u16* wqp = Wtq + (size_t)t*65536;
  const u16* wvp = Wtv + (size_t)t*65536;
  #pragma unroll
  for(int kk=0; kk<8; kk++){
    int kb = kk*32 + quad*8;
    bf16x8 a0 = *(const bf16x8*)(smem + l16*XSP + kb);
    bf16x8 a1 = *(const bf16x8*)(smem + (16+l16)*XSP + kb);
    #pragma unroll
    for(int nt=0; nt<2; nt++){
      int n = cb + w*32 + nt*16 + l16;
      bf16x8 bK = *(const bf16x8*)(wkp + (size_t)n*DD + kb);
      bf16x8 bQ = *(const bf16x8*)(wqp + (size_t)n*DD + kb);
      bf16x8 bV = *(const bf16x8*)(wvp + (size_t)n*DD + kb);
      accK[0][nt] = __builtin_amdgcn_mfma_f32_16x16x32_bf16(a0, bK, accK[0][nt], 0,0,0);
      accK[1][nt] = __builtin_amdgcn_mfma_f32_16x16x32_bf16(a1, bK, accK[1][nt], 0,0,0);
      accQ[0][nt] = __builtin_amdgcn_mfma_f32_16x16x32_bf16(a0, bQ, accQ[0][nt], 0,0,0);
      accQ[1][nt] = __builtin_amdgcn_mfma_f32_16x16x32_bf16(a1, bQ, accQ[1][nt], 0,0,0);
      accV[0][nt] = __builtin_amdgcn_mfma_f32_16x16x32_bf16(a0, bV, accV[0][nt], 0,0,0);
      accV[1][nt] = __builtin_amdgcn_mfma_f32_16x16x32_bf16(a1, bV, accV[1][nt], 0,0,0);
    }
  }
  __syncthreads();                 // x-tile dead; reuse smemb as KV stage (768B rows)
  #pragma unroll
  for(int nt=0; nt<2; nt++){
    int lc = w*32 + nt*16 + l16;   // local col 0..127
    int colg = cb + lc;
    int g12 = (colg >> 2)*12, j = colg & 3;
    float bkv = bk[t*DD+colg], bvv = bv[t*DD+colg];
    #pragma unroll
    for(int mt=0; mt<2; mt++){
      #pragma unroll
      for(int reg=0; reg<4; reg++){
        int row = mt*16 + quad*4 + reg;
        smemb[row*KSP + g12 + j] = f2fp8(accK[mt][nt][reg] + bkv);
        *(u16*)(smemb + row*KSP + g12 + 4 + j*2) = f2bf(accV[mt][nt][reg] + bvv);
      }
    }
  }
  __syncthreads();
  {                                // KV store: 32 rows x 384B (this half) = 768 uint4
    int cbs = (cb >> 2)*12;        // 0 or 384
    #pragma unroll
    for(int it=0; it<3; it++){
      int qq = tid + it*256;
      int row = qq / 24, c = qq - row*24;
      *(uint4*)(KVn + (size_t)(ts+row)*768 + cbs + c*16) =
          *(const uint4*)(smemb + row*KSP + cbs + c*16);
    }
  }
  __syncthreads();                 // KV stage dead; reuse smem as Q stage (bf16)
  #pragma unroll
  for(int nt=0; nt<2; nt++){
    int lc = w*32 + nt*16 + l16;
    float bqv = bq[t*DD + cb + lc];
    #pragma unroll
    for(int mt=0; mt<2; mt++){
      #pragma unroll
      for(int reg=0; reg<4; reg++){
        int row = mt*16 + quad*4 + reg;
        smem[row*XSP + lc] = f2bf(accQ[mt][nt][reg] + bqv);
      }
    }
  }
  __syncthreads();
  #pragma unroll
  for(int it=0; it<2; it++){       // Q write: contiguous rows (perm order), 512 uint4
    int q = tid + it*256;
    int row = q >> 4, c = q & 15;
    *(uint4*)(Qn + (size_t)(ts+row)*DD + cb + c*8) = ((uint4*)(smem + row*XSP))[c];
  }
}

// ---------------- QA bilinear: one block per (tile, r) — 3140 independent blocks -------
// wave w handles heads 2w, 2w+1. Q tile staged in LDS once, Atb is L1/L2-hot (80KB).
#define QSP 264
__global__ __launch_bounds__(256) void k_qa(
    const u16* __restrict__ Qn, const u16* __restrict__ Atb, u16* __restrict__ QA)
{
  __shared__ u16 qs[32*QSP];
  int tid = threadIdx.x;
  int tile = blockIdx.x / NR;        // tile-major: 5 consecutive blocks share Q tile (L2)
  int r = blockIdx.x - tile*NR;
  int ts = tile*32;
  #pragma unroll
  for(int it=0; it<4; it++){         // load Q tile: 32 rows x 32 uint4 (contiguous)
    int q = tid + it*256;
    int row = q >> 5, c = q & 31;
    ((uint4*)(qs + row*QSP))[c] = ((const uint4*)(Qn + (size_t)(ts+row)*DD))[c];
  }
  __syncthreads();
  int lane = tid & 63, w = tid >> 6, quad = lane >> 4, l16 = lane & 15;
  f32x4 acc[2][2][2];                // [hh][mt][nt]
  #pragma unroll
  for(int hh=0;hh<2;hh++)
    #pragma unroll
    for(int mt=0;mt<2;mt++)
      #pragma unroll
      for(int nt=0;nt<2;nt++) acc[hh][mt][nt]=(f32x4)(0.f);
  #pragma unroll
  for(int hh=0; hh<2; hh++){
    int h = w*2 + hh;
    bf16x8 a0 = *(const bf16x8*)(qs + l16*QSP + h*32 + quad*8);
    bf16x8 a1 = *(const bf16x8*)(qs + (16+l16)*QSP + h*32 + quad*8);
    const u16* ap = Atb + (size_t)(r*NH + h)*1024;
    bf16x8 b0 = *(const bf16x8*)(ap + l16*32 + quad*8);
    bf16x8 b1 = *(const bf16x8*)(ap + (16+l16)*32 + quad*8);
    acc[hh][0][0] = __builtin_amdgcn_mfma_f32_16x16x32_bf16(a0, b0, acc[hh][0][0], 0,0,0);
    acc[hh][0][1] = __builtin_amdgcn_mfma_f32_16x16x32_bf16(a0, b1, acc[hh][0][1], 0,0,0);
    acc[hh][1][0] = __builtin_amdgcn_mfma_f32_16x16x32_bf16(a1, b0, acc[hh][1][0], 0,0,0);
    acc[hh][1][1] = __builtin_amdgcn_mfma_f32_16x16x32_bf16(a1, b1, acc[hh][1][1], 0,0,0);
  }
  __syncthreads();                   // Q reads done; reuse qs as output stage
  #pragma unroll
  for(int hh=0; hh<2; hh++){
    int h = w*2 + hh;
    #pragma unroll
    for(int mt=0; mt<2; mt++)
      #pragma unroll
      for(int nt=0; nt<2; nt++)
        #pragma unroll
        for(int reg=0; reg<4; reg++){
          int row = mt*16 + quad*4 + reg;
          qs[row*QSP + h*32 + nt*16 + l16] = f2bf(acc[hh][mt][nt][reg]);
        }
  }
  __syncthreads();
  #pragma unroll
  for(int it=0; it<4; it++){         // QA write: rows ts..ts+31 (perm order), 1024 uint4
    int q = tid + it*256;
    int row = q >> 5, c = q & 31;
    *(uint4*)(QA + ((size_t)(ts+row)*NR + r)*DD + c*8) = ((uint4*)(qs + row*QSP))[c];
  }
}

// ---------------- fused per-node softmax + aggregation: r-sorted, batched gathers ----------
// Barrier-free, 4 nodes/block, 1 wave/node. KV rows now 768B (fp8 K + bf16 V);
// lane loads 12B at lane*12 (dwordx3). The 2^120 fp8-decode scale is folded into q.
__global__ __launch_bounds__(256) void k_edge(
    const unsigned char* __restrict__ KVn, const u16* __restrict__ QA,
    const int* __restrict__ off2, const int* __restrict__ packed,
    const int* __restrict__ perm, u16* __restrict__ aggrV)
{
  int lane = threadIdx.x & 63;
  int p = blockIdx.x*4 + (threadIdx.x >> 6);
  if(p >= NPAD) return;
  int n = perm[p];
  if(n < 0) return;
  int off = lane*4;                  // = h*32 + j*4 with h=lane>>3
  float4 qa[NR];
  {
    const u16* qp = QA + (size_t)p*NR*DD + off;
    const float SC = 0x1.0p120f;     // folds fp8 decode scale; exact (power of 2)
    #pragma unroll
    for(int r=0;r<NR;r++){
      ushort4 q = *(const ushort4*)(qp + r*DD);
      qa[r] = make_float4(bf2f(q.x)*SC,bf2f(q.y)*SC,bf2f(q.z)*SC,bf2f(q.w)*SC);
    }
  }
  int eb[NR+1];
  eb[0] = (n==0) ? 0 : off2[n*NR - 1];
  #pragma unroll
  for(int i=1;i<=NR;i++) eb[i] = off2[n*NR + i - 1];
  float4 acc[NR];
  float s = 0.f;
  int lo12 = lane*12;

  #define EDGE_DOT(kv, q, dd) \
    { u32 _kx = (kv).x; \
      dd = FP8D(_kx & 0xffu)*(q).x + FP8D((_kx>>8) & 0xffu)*(q).y \
         + FP8D((_kx>>16) & 0xffu)*(q).z + FP8D(_kx>>24)*(q).w; }
  #define EDGE_ACC(kv, p, a) \
    { float v0=__uint_as_float((kv).y<<16), v1=__uint_as_float((kv).y&0xffff0000u); \
      float v2=__uint_as_float((kv).z<<16), v3=__uint_as_float((kv).z&0xffff0000u); \
      (a).x += (p)*v0; (a).y += (p)*v1; (a).z += (p)*v2; (a).w += (p)*v3; }
  #define RED3(d) { d += __shfl_xor(d,1); d += __shfl_xor(d,2); d += __shfl_xor(d,4); }

  #pragma unroll
  for(int r=0;r<NR;r++){
    float4 q = qa[r];
    float4 a = make_float4(0.f,0.f,0.f,0.f);
    int e = eb[r], end = eb[r+1];
    for(; e+4 <= end; e += 4){
      int s0 = packed[e], s1 = packed[e+1], s2 = packed[e+2], s3 = packed[e+3];
      u96 kv0 = *(const u96*)(KVn + (size_t)s0*768 + lo12);
      u96 kv1 = *(const u96*)(KVn + (size_t)s1*768 + lo12);
      u96 kv2 = *(const u96*)(KVn + (size_t)s2*768 + lo12);
      u96 kv3 = *(const u96*)(KVn + (size_t)s3*768 + lo12);
      float d0,d1,d2,d3;
      EDGE_DOT(kv0,q,d0); EDGE_DOT(kv1,q,d1); EDGE_DOT(kv2,q,d2); EDGE_DOT(kv3,q,d3);
      RED3(d0); RED3(d1); RED3(d2); RED3(d3);
      float p0=__expf(d0), p1=__expf(d1), p2=__expf(d2), p3=__expf(d3);
      s += p0 + p1 + p2 + p3;
      EDGE_ACC(kv0,p0,a); EDGE_ACC(kv1,p1,a); EDGE_ACC(kv2,p2,a); EDGE_ACC(kv3,p3,a);
    }
    if(e+2 <= end){
      int s0 = packed[e], s1 = packed[e+1];
      u96 kv0 = *(const u96*)(KVn + (size_t)s0*768 + lo12);
      u96 kv1 = *(const u96*)(KVn + (size_t)s1*768 + lo12);
      float d0,d1;
      EDGE_DOT(kv0,q,d0); EDGE_DOT(kv1,q,d1);
      RED3(d0); RED3(d1);
      float p0=__expf(d0), p1=__expf(d1);
      s += p0 + p1;
      EDGE_ACC(kv0,p0,a); EDGE_ACC(kv1,p1,a);
      e += 2;
    }
    if(e < end){
      int s0 = packed[e];
      u96 kv0 = *(const u96*)(KVn + (size_t)s0*768 + lo12);
      float d0;
      EDGE_DOT(kv0,q,d0);
      RED3(d0);
      float p0=__expf(d0);
      s += p0;
      EDGE_ACC(kv0,p0,a);
    }
    acc[r] = a;
  }
  #undef EDGE_DOT
  #undef EDGE_ACC
  #undef RED3
  float inv = (s > 0.f) ? (1.f/s) : 0.f;
  u16* op = aggrV + (size_t)p*NR*DD + off;
  #pragma unroll
  for(int r=0;r<NR;r++){
    ushort4 o;
    o.x=f2bf(acc[r].x*inv); o.y=f2bf(acc[r].y*inv);
    o.z=f2bf(acc[r].z*inv); o.w=f2bf(acc[r].w*inv);
    *(ushort4*)(op + r*DD) = o;
  }
}

// ---------------- FUSED k_msg + k_out (aggrV perm-ordered; stage-1 double-buffered) ------
// Residual read from xb (bf16): halves the gathered x stream (re-quantized right after add).
#define VSP 264
__global__ __launch_bounds__(256) void k_mo(
    const u16* __restrict__ aggrV, const u16* __restrict__ Mtm,
    const u16* __restrict__ xb,
    const int* __restrict__ perm, const int* __restrict__ boff,
    const u16* __restrict__ Wta, const float* __restrict__ ba,
    const u16* __restrict__ Wot, const float* __restrict__ bo,
    float* __restrict__ out)
{
  __shared__ u16 Vs[32*VSP];
  __shared__ u16 hs[32*VSP];
  __shared__ u16 h2s[32*VSP];
  __shared__ int gids[32];
  int tid = threadIdx.x;
  int ts = blockIdx.x*32;
  int t = (ts >= boff[2]) ? 2 : (ts >= boff[1]) ? 1 : 0;
  if(tid < 32) gids[tid] = perm[ts + tid];
  __syncthreads();
  int lane = tid & 63, w = tid >> 6, quad = lane >> 4, l16 = lane & 15;

  // ---- stage 1: rel_msg MFMA over r, double-buffered (Vs / h2s) ----
  f32x4 macc[2][2][2];
  #pragma unroll
  for(int hh=0;hh<2;hh++)
    #pragma unroll
    for(int mt=0;mt<2;mt++)
      #pragma unroll
      for(int nt=0;nt<2;nt++) macc[hh][mt][nt]=(f32x4)(0.f);
  #pragma unroll
  for(int r=0;r<NR;r++){
    u16* B = (r & 1) ? h2s : Vs;
    #pragma unroll
    for(int it=0; it<4; it++){
      int q = tid + it*256;
      int row = q >> 5, c = q & 31;
      ((uint4*)(B + row*VSP))[c] =
        ((const uint4*)(aggrV + ((size_t)(ts+row)*NR + r)*DD))[c];
    }
    __syncthreads();   // single barrier: prior buffer's reads retired before next overwrite
    #pragma unroll
    for(int hh=0; hh<2; hh++){
      int h = w*2 + hh;
      bf16x8 a0 = *(const bf16x8*)(B + l16*VSP + h*32 + quad*8);
      bf16x8 a1 = *(const bf16x8*)(B + (16+l16)*VSP + h*32 + quad*8);
      const u16* mp = Mtm + ((size_t)(r*NH + h)*32)*32;
      bf16x8 b0 = *(const bf16x8*)(mp + l16*32 + quad*8);
      bf16x8 b1 = *(const bf16x8*)(mp + (16+l16)*32 + quad*8);
      macc[hh][0][0] = __builtin_amdgcn_mfma_f32_16x16x32_bf16(a0, b0, macc[hh][0][0], 0,0,0);
      macc[hh][0][1] = __builtin_amdgcn_mfma_f32_16x16x32_bf16(a0, b1, macc[hh][0][1], 0,0,0);
      macc[hh][1][0] = __builtin_amdgcn_mfma_f32_16x16x32_bf16(a1, b0, macc[hh][1][0], 0,0,0);
      macc[hh][1][1] = __builtin_amdgcn_mfma_f32_16x16x32_bf16(a1, b1, macc[hh][1][1], 0,0,0);
    }
  }
  // ELU -> hs (bf16, in LDS)
  #pragma unroll
  for(int hh=0; hh<2; hh++){
    int h = w*2 + hh;
    #pragma unroll
    for(int mt=0; mt<2; mt++){
      #pragma unroll
      for(int nt=0; nt<2; nt++){
        #pragma unroll
        for(int reg=0; reg<4; reg++){
          int row = mt*16 + quad*4 + reg;
          float v = macc[hh][mt][nt][reg];
          v = (v > 0.f) ? v : expm1f(v);
          hs[row*VSP + h*32 + nt*16 + l16] = f2bf(v);
        }
      }
    }
  }
  __syncthreads();

  // ---- stage 2: Wa MFMA + residual + classifier + log_softmax ----
  f32x4 acc[2][4];
  #pragma unroll
  for(int mt=0;mt<2;mt++)
    #pragma unroll
    for(int nt=0;nt<4;nt++) acc[mt][nt]=(f32x4)(0.f);
  const u16* wap = Wta + (size_t)t*65536;
  #pragma unroll
  for(int kk=0; kk<8; kk++){
    int kb = kk*32 + quad*8;
    bf16x8 a0 = *(const bf16x8*)(hs + l16*VSP + kb);
    bf16x8 a1 = *(const bf16x8*)(hs + (16+l16)*VSP + kb);
    #pragma unroll
    for(int nt=0; nt<4; nt++){
      int n = w*64 + nt*16 + l16;
      bf16x8 b = *(const bf16x8*)(wap + (size_t)n*DD + kb);
      acc[0][nt] = __builtin_amdgcn_mfma_f32_16x16x32_bf16(a0, b, acc[0][nt], 0,0,0);
      acc[1][nt] = __builtin_amdgcn_mfma_f32_16x16x32_bf16(a1, b, acc[1][nt], 0,0,0);
    }
  }
  #pragma unroll
  for(int nt=0; nt<4; nt++){
    int colg = w*64 + nt*16 + l16;
    float bav = ba[t*DD + colg];
    #pragma unroll
    for(int mt=0; mt<2; mt++){
      #pragma unroll
      for(int reg=0; reg<4; reg++){
        int row = mt*16 + quad*4 + reg;
        int g = gids[row];
        float xr = (g>=0) ? bf2f(xb[(size_t)g*DD + colg]) : 0.f;
        h2s[row*VSP + colg] = f2bf(acc[mt][nt][reg] + bav + xr);
      }
    }
  }
  __syncthreads();
  if(w < 2){
    f32x4 cacc = (f32x4)(0.f);
    #pragma unroll
    for(int kk=0; kk<8; kk++){
      int kb = kk*32 + quad*8;
      bf16x8 a = *(const bf16x8*)(h2s + (w*16 + l16)*VSP + kb);
      bf16x8 b = *(const bf16x8*)(Wot + (size_t)l16*DD + kb);
      cacc = __builtin_amdgcn_mfma_f32_16x16x32_bf16(a, b, cacc, 0,0,0);
    }
    float bov = bo[l16];
    #pragma unroll
    for(int reg=0; reg<4; reg++){
      int row = w*16 + quad*4 + reg;
      int g = gids[row];
      float v = cacc[reg] + bov;     // col = l16 = class
      float m = v;
      m = fmaxf(m, __shfl_xor(m,1)); m = fmaxf(m, __shfl_xor(m,2));
      m = fmaxf(m, __shfl_xor(m,4)); m = fmaxf(m, __shfl_xor(m,8));
      float p = __expf(v - m);
      p += __shfl_xor(p,1); p += __shfl_xor(p,2);
      p += __shfl_xor(p,4); p += __shfl_xor(p,8);
      float lse = m + __logf(p);
      if(g >= 0) out[(size_t)g*NC + l16] = v - lse;
    }
  }
}

extern "C" void kernel_launch(void* const* d_in, const int* in_sizes, int n_in,
                              void* d_out, int out_size, void* d_ws, size_t ws_size,
                              hipStream_t stream)
{
  const float* x     = (const float*)d_in[0];
  const int*   ei    = (const int*)d_in[1];
  const int*   ntype = (const int*)d_in[2];
  const int*   etype = (const int*)d_in[3];
  const float* Wk    = (const float*)d_in[4];
  const float* bk    = (const float*)d_in[5];
  const float* Wq    = (const float*)d_in[6];
  const float* bq    = (const float*)d_in[7];
  const float* Wv    = (const float*)d_in[8];
  const float* bv    = (const float*)d_in[9];
  const float* Wa    = (const float*)d_in[10];
  const float* ba    = (const float*)d_in[11];
  const float* prior = (const float*)d_in[12];
  const float* ratt  = (const float*)d_in[13];
  const float* rmsg  = (const float*)d_in[14];
  const float* Wo    = (const float*)d_in[15];
  const float* bo    = (const float*)d_in[16];
  float* out = (float*)d_out;

  char* ws = (char*)d_ws;
  int* iw      = (int*)ws;
  int* cnt     = iw + 0;
  int* bcur    = iw + 4;
  int* boff    = iw + 8;
  int* off2    = iw + 16;                 // NN*NR+1 = 100001 ints
  int* perm    = iw + 100032;             // 20096 ints
  int* packed  = iw + 120128;             // NE ints (ends 440128)
  int* bsum    = iw + 440128;             // 512 ints (ends 440640)
  int* pos2    = iw + 440640;             // NN ints (ends 460640)

  size_t fb = 1842688;                    // 460640*4 = 1842560, 256-aligned up
  unsigned char* KVn = (unsigned char*)(ws + fb); fb += 768ull*NPAD;  // 15.43 MB (fp8 K + bf16 V)
  u16*   Qn    = (u16*)(ws + fb);   fb += 2ull*NPAD*DD;         // 10.29 MB (perm order)
  u16*   QA    = (u16*)(ws + fb);   fb += 2ull*NPAD*NR*DD;      // 51.45 MB (perm order)
  u16*   aggrV = (u16*)(ws + fb);   fb += 2ull*NPAD*NR*DD;      // 51.45 MB (perm order)
  u16*   xb    = (u16*)(ws + fb);   fb += 2ull*NN*DD;           // 10.24 MB (dedicated: k_mo residual)
  u16*   Wtk   = (u16*)(ws + fb);   fb += 2ull*3*65536;
  u16*   Wtq   = (u16*)(ws + fb);   fb += 2ull*3*65536;
  u16*   Wtv   = (u16*)(ws + fb);   fb += 2ull*3*65536;
  u16*   Wta   = (u16*)(ws + fb);   fb += 2ull*3*65536;
  u16*   Wot   = (u16*)(ws + fb);   fb += 2ull*NC*DD;
  u16*   Mtm   = (u16*)(ws + fb);   fb += 2ull*NR*NH*KK*KK;
  u16*   Atb   = (u16*)(ws + fb);   fb += 2ull*NR*NH*KK*KK;
  // total ~142 MB (validated high-water mark: 165.6 MB)

  hipMemsetAsync(iw, 0, (size_t)(16 + NN*NR + 1)*sizeof(int), stream); // cnt,bcur,boff,off2

  k_pre1   <<<1408, 256, 0, stream>>>(ntype, ei, etype, cnt, off2, perm);
  k_pre2   <<<NB2+1, 256, 0, stream>>>(off2, bsum, cnt, boff);
  k_scan2  <<<1, 512, 0, stream>>>(bsum, off2);
  k_pre3   <<<NB2+79, 256, 0, stream>>>(off2, bsum, ntype, boff, bcur, perm, pos2);
  k_work1  <<<4854, 256, 0, stream>>>(ei, etype, off2, packed, pos2, x, xb,
                                      Wk, Wq, Wv, Wa, Wtk, Wtq, Wtv, Wta,
                                      rmsg, ratt, prior, Wo, Mtm, Atb, Wot);
  k_projqa <<<1256, 256, 0, stream>>>(xb, perm, boff, Wtk, Wtq, Wtv, bk, bq, bv,
                                      KVn, Qn);
  k_qa     <<<628*NR, 256, 0, stream>>>(Qn, Atb, QA);
  k_edge   <<<5024, 256, 0, stream>>>(KVn, QA, off2, packed, perm, aggrV);
  k_mo     <<<628, 256, 0, stream>>>(aggrV, Mtm, xb, perm, boff, Wta, ba, Wot, bo, out);
}

// Round 7
// 299.675 us; speedup vs baseline: 1.0158x; 1.0158x over previous
//
#include <hip/hip_runtime.h>
#include <hip/hip_bf16.h>
#include <math.h>

#define NN 20000
#define NE 320000
#define DD 256
#define NH 8
#define KK 32
#define NR 5
#define NC 16
#define NPAD 20096  // perm-padded row count (boff 32-aligned, 3 types)
#define EPB 1024    // scan elements per block
#define NBS 98      // ceil(NN*NR / EPB)

typedef unsigned short u16;
typedef unsigned int u32;
typedef unsigned long long u64;
typedef __attribute__((ext_vector_type(8))) short bf16x8;
typedef __attribute__((ext_vector_type(4))) float f32x4;

__device__ __forceinline__ float bf2f(u16 v){ return __uint_as_float(((u32)v)<<16); }
__device__ __forceinline__ u16 f2bf(float f){
  u32 u = __float_as_uint(f);
  return (u16)((u + 0x7FFFu + ((u>>16)&1u)) >> 16);
}
// OCP e4m3fn software encode (RNE). |f| << 448 here (K projections ~ N(0,1)).
__device__ __forceinline__ unsigned char f2fp8(float f){
  u32 b = __float_as_uint(f * 0x1.0p-120f);   // e4m3 exp/mant now at bits 26..20
  u32 s = (b >> 24) & 0x80u;
  u32 m = b & 0x7fffffffu;
  u32 r = m + 0x7FFFFu + ((m >> 20) & 1u);    // RNE at bit 20
  return (unsigned char)(s | ((r >> 20) & 0x7fu));
}
// decode (value scaled by 2^-120; the 2^120 is pre-folded into q registers)
#define FP8D(t) __uint_as_float((((t)&0x80u)<<24) | (((t)&0x7fu)<<20))

struct u96 { u32 x, y, z; };   // 12B, align 4 (dwordx3-friendly)

// ---------------- pre1: nb_count + deg + perm=-1 init (independent block ranges) --------
__global__ void k_pre1(const int* __restrict__ ntype, const int* __restrict__ ei,
                       const int* __restrict__ etype, int* __restrict__ cnt,
                       int* __restrict__ off2, int* __restrict__ perm){
  int b = blockIdx.x;
  if(b < 79){
    int n = b*256 + threadIdx.x;
    int t = (n < NN) ? ntype[n] : -1;
    int lane = threadIdx.x & 63;
    #pragma unroll
    for(int tt=0; tt<3; tt++){
      unsigned long long mask = __ballot(t == tt);
      int leader = __ffsll((long long)mask) - 1;
      if(lane == leader) atomicAdd(&cnt[tt], __popcll(mask));
    }
  } else if(b < 1329){
    int e = (b-79)*256 + threadIdx.x;
    if(e < NE) atomicAdd(&off2[ei[NE + e]*NR + etype[e]], 1);
  } else {
    int i = (b-1329)*256 + threadIdx.x;
    if(i < NPAD) perm[i] = -1;
  }
}

// ---------------- k_scan: ONE-kernel decoupled-lookback exclusive scan + nb_scatter -----
// Replaces pre2 + scan2 + pre3 (3 launches -> 1). Blocks 0..NBS-1: scan 1024 counts each
// (int4 loads, LDS scan of 256 thread-sums, u64 atomic publish: status<<32|value,
// status 1=aggregate 2=inclusive). 177 blocks total -> all co-resident, spin is safe.
// Blocks NBS..NBS+78: nb_scatter (perm/pos2); boff computed locally from cnt (pre1 output).
__global__ __launch_bounds__(256) void k_scan(
    int* __restrict__ off2, u64* __restrict__ lb,
    const int* __restrict__ cnt, const int* __restrict__ ntype,
    int* __restrict__ bcur, int* __restrict__ perm,
    int* __restrict__ pos2, int* __restrict__ boff)
{
  int b = blockIdx.x;
  if(b < NBS){
    __shared__ int sh[256];
    __shared__ int exoff_s;
    int t = threadIdx.x;
    int base = b*EPB + t*4;
    int4 v = make_int4(0,0,0,0);
    if(base < NN*NR) v = *(const int4*)(off2 + base);
    int ts = v.x + v.y + v.z + v.w;
    sh[t] = ts;
    __syncthreads();
    for(int off=1; off<256; off<<=1){
      int val = (t >= off) ? sh[t-off] : 0;
      __syncthreads();
      sh[t] += val;
      __syncthreads();
    }
    int btot = sh[255];
    if(t == 0){
      if(b == 0){
        atomicExch(&lb[0], (2ull<<32) | (u32)btot);
        exoff_s = 0;
      } else {
        atomicExch(&lb[b], (1ull<<32) | (u32)btot);
        int sum = 0, j = b-1;
        while(true){
          u64 s = atomicAdd(&lb[j], 0ull);    // device-scope read
          u32 st = (u32)(s >> 32);
          if(st == 0) continue;               // predecessor not published yet
          sum += (int)(u32)s;
          if(st == 2) break;                  // hit an inclusive prefix
          --j;
        }
        atomicExch(&lb[b], (2ull<<32) | (u32)(sum + btot));
        exoff_s = sum;
      }
    }
    __syncthreads();
    int ex = exoff_s + sh[t] - ts;            // global exclusive before this thread's 4
    if(base < NN*NR){
      int4 o;
      o.x = ex; o.y = ex + v.x; o.z = ex + v.x + v.y; o.w = ex + v.x + v.y + v.z;
      *(int4*)(off2 + base) = o;
    }
  } else {
    int a32 = (cnt[0]+31)&~31;
    int b32 = (cnt[1]+31)&~31;
    if(b == NBS && threadIdx.x == 0){ boff[0]=0; boff[1]=a32; boff[2]=a32+b32; }
    int boffl[3] = {0, a32, a32 + b32};
    int n = (b - NBS)*256 + threadIdx.x;
    int t = (n < NN) ? ntype[n] : -1;
    int lane = threadIdx.x & 63;
    #pragma unroll
    for(int tt=0; tt<3; tt++){
      unsigned long long mask = __ballot(t == tt);
      if(t == tt){
        int rank = __popcll(mask & ((1ull<<lane)-1ull));
        int leader = __ffsll((long long)mask) - 1;
        int base2 = 0;
        if(lane == leader) base2 = atomicAdd(&bcur[tt], __popcll(mask));
        base2 = __shfl(base2, leader);
        int p = boffl[tt] + base2 + rank;
        perm[p] = n;
        pos2[n] = p;               // inverse perm: KVn/Qn/QA/aggrV all perm-ordered
      }
    }
  }
}

// ---------------- work1: escatter + castx + castw + castsmall (independent ranges) ------
// escatter stores PERM POSITIONS of src (pos2[src]) so KVn can be perm-ordered.
__global__ __launch_bounds__(256) void k_work1(
    const int* __restrict__ ei, const int* __restrict__ etype,
    int* __restrict__ off2, int* __restrict__ packed,
    const int* __restrict__ pos2,
    const float* __restrict__ x, u16* __restrict__ xb,
    const float* __restrict__ Wk, const float* __restrict__ Wq,
    const float* __restrict__ Wv, const float* __restrict__ Wa,
    u16* __restrict__ Wtk, u16* __restrict__ Wtq,
    u16* __restrict__ Wtv, u16* __restrict__ Wta,
    const float* __restrict__ rmsg, const float* __restrict__ ratt,
    const float* __restrict__ prior, const float* __restrict__ Wo,
    u16* __restrict__ Mtm, u16* __restrict__ Atb, u16* __restrict__ Wot)
{
  __shared__ float tile[32][33];
  int b = blockIdx.x;
  if(b < 1250){
    int e = b*256 + threadIdx.x;
    if(e < NE){
      int pos = atomicAdd(&off2[ei[NE+e]*NR + etype[e]], 1);
      packed[pos] = pos2[ei[e]];
    }
  } else if(b < 3750){
    int i = (b-1250)*256 + threadIdx.x;     // castx: 8 floats per thread
    float4 v0 = ((const float4*)x)[i*2+0];
    float4 v1 = ((const float4*)x)[i*2+1];
    uint4 o;
    o.x = (u32)f2bf(v0.x) | ((u32)f2bf(v0.y)<<16);
    o.y = (u32)f2bf(v0.z) | ((u32)f2bf(v0.w)<<16);
    o.z = (u32)f2bf(v1.x) | ((u32)f2bf(v1.y)<<16);
    o.w = (u32)f2bf(v1.z) | ((u32)f2bf(v1.w)<<16);
    ((uint4*)xb)[i] = o;
  } else if(b < 4518){
    int bp = b - 3750;                      // castw: 768 tiles = 8 x 8 x 12
    int bx = bp & 7, by = (bp>>3) & 7, z = bp >> 6;
    int tensor = z/3, t = z%3;
    const float* W = (tensor==0) ? Wk : (tensor==1) ? Wq : (tensor==2) ? Wv : Wa;
    u16* O = (tensor==0) ? Wtk : (tensor==1) ? Wtq : (tensor==2) ? Wtv : Wta;
    int i0 = bx*32, j0 = by*32;
    int rr = threadIdx.x>>5, cc = threadIdx.x&31;
    #pragma unroll
    for(int p=0;p<4;p++)
      tile[rr+p*8][cc] = W[t*65536 + (i0+rr+p*8)*256 + j0+cc];
    __syncthreads();
    #pragma unroll
    for(int p=0;p<4;p++)
      O[t*65536 + (j0+rr+p*8)*256 + i0+cc] = f2bf(tile[cc][rr+p*8]);
  } else {
    int bp = b - 4518;                      // castsmall: 336 blocks
    if(bp < 160){
      int idx = bp*256 + threadIdx.x;       // rel_msg transpose: [r,h,k,l] -> [r,h,l,k]
      int l = idx & 31, k = (idx >> 5) & 31, rh = idx >> 10;
      Mtm[(rh*32 + l)*32 + k] = f2bf(rmsg[idx]);
    } else if(bp < 320){
      int idx = (bp-160)*256 + threadIdx.x; // rel_att cast w/ prior/sqrtK folded
      int rh = idx >> 10;
      float scale = prior[rh] * 0.17677669529663687f;  // 1/sqrt(32)
      Atb[idx] = f2bf(ratt[idx] * scale);
    } else {
      int idx = (bp-320)*256 + threadIdx.x; // W_out transpose: [k,c] -> [c,k]
      int c = idx & 15, k = idx >> 4;
      Wot[c*DD + k] = f2bf(Wo[k*NC + c]);
    }
  }
}

// ---------------- FUSED typed K/Q/V projections --------
// KVn rows 768B: per 4-dim group g: [K 4x fp8e4m3][V 4x bf16] at byte g*12.
// K fp8 cuts k_edge's gathered row from 1KB to 768B (k_edge is delivered-bytes-bound).
#define XSP 264   // padded row (u16) for x-tile / Q stages
#define KSP 784   // padded row (bytes) for KV stage (768 + 16)
__global__ __launch_bounds__(256) void k_projqa(
    const u16* __restrict__ xb, const int* __restrict__ perm, const int* __restrict__ boff,
    const u16* __restrict__ Wtk, const u16* __restrict__ Wtq, const u16* __restrict__ Wtv,
    const float* __restrict__ bk, const float* __restrict__ bq, const float* __restrict__ bv,
    unsigned char* __restrict__ KVn, u16* __restrict__ Qn)
{
  __shared__ unsigned char smemb[32*KSP];   // x-tile (u16 view) -> KV-stage (bytes) -> Q-stage
  __shared__ int gids[32];
  u16* smem = (u16*)smemb;
  int tid = threadIdx.x;
  int ts = (blockIdx.x >> 1)*32;
  int cb = (blockIdx.x & 1)*128;          // column base for this block
  int t = (ts >= boff[2]) ? 2 : (ts >= boff[1]) ? 1 : 0;   // boff 32-aligned
  if(tid < 32) gids[tid] = perm[ts + tid];
  __syncthreads();
  #pragma unroll
  for(int it=0; it<4; it++){
    int q = tid + it*256;
    int row = q >> 5, c = q & 31;
    int g = gids[row];
    uint4 v = make_uint4(0,0,0,0);
    if(g >= 0) v = ((const uint4*)(xb + (size_t)g*DD))[c];
    ((uint4*)(smem + row*XSP))[c] = v;
  }
  __syncthreads();
  int lane = tid & 63;
  int w = tid >> 6;
  int quad = lane >> 4;
  int l16 = lane & 15;
  f32x4 accK[2][2], accQ[2][2], accV[2][2];   // [mt][nt]
  #pragma unroll
  for(int mt=0;mt<2;mt++)
    #pragma unroll
    for(int nt=0;nt<2;nt++){
      accK[mt][nt]=(f32x4)(0.f); accQ[mt][nt]=(f32x4)(0.f); accV[mt][nt]=(f32x4)(0.f);
    }
  const u16* wkp = Wtk + (size_t)t*65536;
  const u16* wqp = Wtq + (size_t)t*65536;
  const u16* wvp = Wtv + (size_t)t*65536;
  #pragma unroll
  for(int kk=0; kk<8; kk++){
    int kb = kk*32 + quad*8;
    bf16x8 a0 = *(const bf16x8*)(smem + l16*XSP + kb);
    bf16x8 a1 = *(const bf16x8*)(smem + (16+l16)*XSP + kb);
    #pragma unroll
    for(int nt=0; nt<2; nt++){
      int n = cb + w*32 + nt*16 + l16;
      bf16x8 bK = *(const bf16x8*)(wkp + (size_t)n*DD + kb);
      bf16x8 bQ = *(const bf16x8*)(wqp + (size_t)n*DD + kb);
      bf16x8 bV = *(const bf16x8*)(wvp + (size_t)n*DD + kb);
      accK[0][nt] = __builtin_amdgcn_mfma_f32_16x16x32_bf16(a0, bK, accK[0][nt], 0,0,0);
      accK[1][nt] = __builtin_amdgcn_mfma_f32_16x16x32_bf16(a1, bK, accK[1][nt], 0,0,0);
      accQ[0][nt] = __builtin_amdgcn_mfma_f32_16x16x32_bf16(a0, bQ, accQ[0][nt], 0,0,0);
      accQ[1][nt] = __builtin_amdgcn_mfma_f32_16x16x32_bf16(a1, bQ, accQ[1][nt], 0,0,0);
      accV[0][nt] = __builtin_amdgcn_mfma_f32_16x16x32_bf16(a0, bV, accV[0][nt], 0,0,0);
      accV[1][nt] = __builtin_amdgcn_mfma_f32_16x16x32_bf16(a1, bV, accV[1][nt], 0,0,0);
    }
  }
  __syncthreads();                 // x-tile dead; reuse smemb as KV stage (768B rows)
  #pragma unroll
  for(int nt=0; nt<2; nt++){
    int lc = w*32 + nt*16 + l16;   // local col 0..127
    int colg = cb + lc;
    int g12 = (colg >> 2)*12, j = colg & 3;
    float bkv = bk[t*DD+colg], bvv = bv[t*DD+colg];
    #pragma unroll
    for(int mt=0; mt<2; mt++){
      #pragma unroll
      for(int reg=0; reg<4; reg++){
        int row = mt*16 + quad*4 + reg;
        smemb[row*KSP + g12 + j] = f2fp8(accK[mt][nt][reg] + bkv);
        *(u16*)(smemb + row*KSP + g12 + 4 + j*2) = f2bf(accV[mt][nt][reg] + bvv);
      }
    }
  }
  __syncthreads();
  {                                // KV store: 32 rows x 384B (this half) = 768 uint4
    int cbs = (cb >> 2)*12;        // 0 or 384
    #pragma unroll
    for(int it=0; it<3; it++){
      int qq = tid + it*256;
      int row = qq / 24, c = qq - row*24;
      *(uint4*)(KVn + (size_t)(ts+row)*768 + cbs + c*16) =
          *(const uint4*)(smemb + row*KSP + cbs + c*16);
    }
  }
  __syncthreads();                 // KV stage dead; reuse smem as Q stage (bf16)
  #pragma unroll
  for(int nt=0; nt<2; nt++){
    int lc = w*32 + nt*16 + l16;
    float bqv = bq[t*DD + cb + lc];
    #pragma unroll
    for(int mt=0; mt<2; mt++){
      #pragma unroll
      for(int reg=0; reg<4; reg++){
        int row = mt*16 + quad*4 + reg;
        smem[row*XSP + lc] = f2bf(accQ[mt][nt][reg] + bqv);
      }
    }
  }
  __syncthreads();
  #pragma unroll
  for(int it=0; it<2; it++){       // Q write: contiguous rows (perm order), 512 uint4
    int q = tid + it*256;
    int row = q >> 4, c = q & 15;
    *(uint4*)(Qn + (size_t)(ts+row)*DD + cb + c*8) = ((uint4*)(smem + row*XSP))[c];
  }
}

// ---------------- QA bilinear: one block per (tile, r) — 3140 independent blocks -------
// wave w handles heads 2w, 2w+1. Q tile staged in LDS once, Atb is L1/L2-hot (80KB).
#define QSP 264
__global__ __launch_bounds__(256) void k_qa(
    const u16* __restrict__ Qn, const u16* __restrict__ Atb, u16* __restrict__ QA)
{
  __shared__ u16 qs[32*QSP];
  int tid = threadIdx.x;
  int tile = blockIdx.x / NR;        // tile-major: 5 consecutive blocks share Q tile (L2)
  int r = blockIdx.x - tile*NR;
  int ts = tile*32;
  #pragma unroll
  for(int it=0; it<4; it++){         // load Q tile: 32 rows x 32 uint4 (contiguous)
    int q = tid + it*256;
    int row = q >> 5, c = q & 31;
    ((uint4*)(qs + row*QSP))[c] = ((const uint4*)(Qn + (size_t)(ts+row)*DD))[c];
  }
  __syncthreads();
  int lane = tid & 63, w = tid >> 6, quad = lane >> 4, l16 = lane & 15;
  f32x4 acc[2][2][2];                // [hh][mt][nt]
  #pragma unroll
  for(int hh=0;hh<2;hh++)
    #pragma unroll
    for(int mt=0;mt<2;mt++)
      #pragma unroll
      for(int nt=0;nt<2;nt++) acc[hh][mt][nt]=(f32x4)(0.f);
  #pragma unroll
  for(int hh=0; hh<2; hh++){
    int h = w*2 + hh;
    bf16x8 a0 = *(const bf16x8*)(qs + l16*QSP + h*32 + quad*8);
    bf16x8 a1 = *(const bf16x8*)(qs + (16+l16)*QSP + h*32 + quad*8);
    const u16* ap = Atb + (size_t)(r*NH + h)*1024;
    bf16x8 b0 = *(const bf16x8*)(ap + l16*32 + quad*8);
    bf16x8 b1 = *(const bf16x8*)(ap + (16+l16)*32 + quad*8);
    acc[hh][0][0] = __builtin_amdgcn_mfma_f32_16x16x32_bf16(a0, b0, acc[hh][0][0], 0,0,0);
    acc[hh][0][1] = __builtin_amdgcn_mfma_f32_16x16x32_bf16(a0, b1, acc[hh][0][1], 0,0,0);
    acc[hh][1][0] = __builtin_amdgcn_mfma_f32_16x16x32_bf16(a1, b0, acc[hh][1][0], 0,0,0);
    acc[hh][1][1] = __builtin_amdgcn_mfma_f32_16x16x32_bf16(a1, b1, acc[hh][1][1], 0,0,0);
  }
  __syncthreads();                   // Q reads done; reuse qs as output stage
  #pragma unroll
  for(int hh=0; hh<2; hh++){
    int h = w*2 + hh;
    #pragma unroll
    for(int mt=0; mt<2; mt++)
      #pragma unroll
      for(int nt=0; nt<2; nt++)
        #pragma unroll
        for(int reg=0; reg<4; reg++){
          int row = mt*16 + quad*4 + reg;
          qs[row*QSP + h*32 + nt*16 + l16] = f2bf(acc[hh][mt][nt][reg]);
        }
  }
  __syncthreads();
  #pragma unroll
  for(int it=0; it<4; it++){         // QA write: rows ts..ts+31 (perm order), 1024 uint4
    int q = tid + it*256;
    int row = q >> 5, c = q & 31;
    *(uint4*)(QA + ((size_t)(ts+row)*NR + r)*DD + c*8) = ((uint4*)(qs + row*QSP))[c];
  }
}

// ---------------- fused per-node softmax + aggregation: r-sorted, batched gathers ----------
// Barrier-free, 4 nodes/block, 1 wave/node. KV rows 768B (fp8 K + bf16 V);
// lane loads 12B at lane*12 (dwordx3). The 2^120 fp8-decode scale is folded into q.
__global__ __launch_bounds__(256) void k_edge(
    const unsigned char* __restrict__ KVn, const u16* __restrict__ QA,
    const int* __restrict__ off2, const int* __restrict__ packed,
    const int* __restrict__ perm, u16* __restrict__ aggrV)
{
  int lane = threadIdx.x & 63;
  int p = blockIdx.x*4 + (threadIdx.x >> 6);
  if(p >= NPAD) return;
  int n = perm[p];
  if(n < 0) return;
  int off = lane*4;                  // = h*32 + j*4 with h=lane>>3
  float4 qa[NR];
  {
    const u16* qp = QA + (size_t)p*NR*DD + off;
    const float SC = 0x1.0p120f;     // folds fp8 decode scale; exact (power of 2)
    #pragma unroll
    for(int r=0;r<NR;r++){
      ushort4 q = *(const ushort4*)(qp + r*DD);
      qa[r] = make_float4(bf2f(q.x)*SC,bf2f(q.y)*SC,bf2f(q.z)*SC,bf2f(q.w)*SC);
    }
  }
  int eb[NR+1];
  eb[0] = (n==0) ? 0 : off2[n*NR - 1];
  #pragma unroll
  for(int i=1;i<=NR;i++) eb[i] = off2[n*NR + i - 1];
  float4 acc[NR];
  float s = 0.f;
  int lo12 = lane*12;

  #define EDGE_DOT(kv, q, dd) \
    { u32 _kx = (kv).x; \
      dd = FP8D(_kx & 0xffu)*(q).x + FP8D((_kx>>8) & 0xffu)*(q).y \
         + FP8D((_kx>>16) & 0xffu)*(q).z + FP8D(_kx>>24)*(q).w; }
  #define EDGE_ACC(kv, p, a) \
    { float v0=__uint_as_float((kv).y<<16), v1=__uint_as_float((kv).y&0xffff0000u); \
      float v2=__uint_as_float((kv).z<<16), v3=__uint_as_float((kv).z&0xffff0000u); \
      (a).x += (p)*v0; (a).y += (p)*v1; (a).z += (p)*v2; (a).w += (p)*v3; }
  #define RED3(d) { d += __shfl_xor(d,1); d += __shfl_xor(d,2); d += __shfl_xor(d,4); }

  #pragma unroll
  for(int r=0;r<NR;r++){
    float4 q = qa[r];
    float4 a = make_float4(0.f,0.f,0.f,0.f);
    int e = eb[r], end = eb[r+1];
    for(; e+4 <= end; e += 4){
      int s0 = packed[e], s1 = packed[e+1], s2 = packed[e+2], s3 = packed[e+3];
      u96 kv0 = *(const u96*)(KVn + (size_t)s0*768 + lo12);
      u96 kv1 = *(const u96*)(KVn + (size_t)s1*768 + lo12);
      u96 kv2 = *(const u96*)(KVn + (size_t)s2*768 + lo12);
      u96 kv3 = *(const u96*)(KVn + (size_t)s3*768 + lo12);
      float d0,d1,d2,d3;
      EDGE_DOT(kv0,q,d0); EDGE_DOT(kv1,q,d1); EDGE_DOT(kv2,q,d2); EDGE_DOT(kv3,q,d3);
      RED3(d0); RED3(d1); RED3(d2); RED3(d3);
      float p0=__expf(d0), p1=__expf(d1), p2=__expf(d2), p3=__expf(d3);
      s += p0 + p1 + p2 + p3;
      EDGE_ACC(kv0,p0,a); EDGE_ACC(kv1,p1,a); EDGE_ACC(kv2,p2,a); EDGE_ACC(kv3,p3,a);
    }
    if(e+2 <= end){
      int s0 = packed[e], s1 = packed[e+1];
      u96 kv0 = *(const u96*)(KVn + (size_t)s0*768 + lo12);
      u96 kv1 = *(const u96*)(KVn + (size_t)s1*768 + lo12);
      float d0,d1;
      EDGE_DOT(kv0,q,d0); EDGE_DOT(kv1,q,d1);
      RED3(d0); RED3(d1);
      float p0=__expf(d0), p1=__expf(d1);
      s += p0 + p1;
      EDGE_ACC(kv0,p0,a); EDGE_ACC(kv1,p1,a);
      e += 2;
    }
    if(e < end){
      int s0 = packed[e];
      u96 kv0 = *(const u96*)(KVn + (size_t)s0*768 + lo12);
      float d0;
      EDGE_DOT(kv0,q,d0);
      RED3(d0);
      float p0=__expf(d0);
      s += p0;
      EDGE_ACC(kv0,p0,a);
    }
    acc[r] = a;
  }
  #undef EDGE_DOT
  #undef EDGE_ACC
  #undef RED3
  float inv = (s > 0.f) ? (1.f/s) : 0.f;
  u16* op = aggrV + (size_t)p*NR*DD + off;
  #pragma unroll
  for(int r=0;r<NR;r++){
    ushort4 o;
    o.x=f2bf(acc[r].x*inv); o.y=f2bf(acc[r].y*inv);
    o.z=f2bf(acc[r].z*inv); o.w=f2bf(acc[r].w*inv);
    *(ushort4*)(op + r*DD) = o;
  }
}

// ---------------- FUSED k_msg + k_out (aggrV perm-ordered; stage-1 double-buffered) ------
// Residual read from xb (bf16): halves the gathered x stream (re-quantized right after add).
#define VSP 264
__global__ __launch_bounds__(256) void k_mo(
    const u16* __restrict__ aggrV, const u16* __restrict__ Mtm,
    const u16* __restrict__ xb,
    const int* __restrict__ perm, const int* __restrict__ boff,
    const u16* __restrict__ Wta, const float* __restrict__ ba,
    const u16* __restrict__ Wot, const float* __restrict__ bo,
    float* __restrict__ out)
{
  __shared__ u16 Vs[32*VSP];
  __shared__ u16 hs[32*VSP];
  __shared__ u16 h2s[32*VSP];
  __shared__ int gids[32];
  int tid = threadIdx.x;
  int ts = blockIdx.x*32;
  int t = (ts >= boff[2]) ? 2 : (ts >= boff[1]) ? 1 : 0;
  if(tid < 32) gids[tid] = perm[ts + tid];
  __syncthreads();
  int lane = tid & 63, w = tid >> 6, quad = lane >> 4, l16 = lane & 15;

  // ---- stage 1: rel_msg MFMA over r, double-buffered (Vs / h2s) ----
  f32x4 macc[2][2][2];
  #pragma unroll
  for(int hh=0;hh<2;hh++)
    #pragma unroll
    for(int mt=0;mt<2;mt++)
      #pragma unroll
      for(int nt=0;nt<2;nt++) macc[hh][mt][nt]=(f32x4)(0.f);
  #pragma unroll
  for(int r=0;r<NR;r++){
    u16* B = (r & 1) ? h2s : Vs;
    #pragma unroll
    for(int it=0; it<4; it++){
      int q = tid + it*256;
      int row = q >> 5, c = q & 31;
      ((uint4*)(B + row*VSP))[c] =
        ((const uint4*)(aggrV + ((size_t)(ts+row)*NR + r)*DD))[c];
    }
    __syncthreads();   // single barrier: prior buffer's reads retired before next overwrite
    #pragma unroll
    for(int hh=0; hh<2; hh++){
      int h = w*2 + hh;
      bf16x8 a0 = *(const bf16x8*)(B + l16*VSP + h*32 + quad*8);
      bf16x8 a1 = *(const bf16x8*)(B + (16+l16)*VSP + h*32 + quad*8);
      const u16* mp = Mtm + ((size_t)(r*NH + h)*32)*32;
      bf16x8 b0 = *(const bf16x8*)(mp + l16*32 + quad*8);
      bf16x8 b1 = *(const bf16x8*)(mp + (16+l16)*32 + quad*8);
      macc[hh][0][0] = __builtin_amdgcn_mfma_f32_16x16x32_bf16(a0, b0, macc[hh][0][0], 0,0,0);
      macc[hh][0][1] = __builtin_amdgcn_mfma_f32_16x16x32_bf16(a0, b1, macc[hh][0][1], 0,0,0);
      macc[hh][1][0] = __builtin_amdgcn_mfma_f32_16x16x32_bf16(a1, b0, macc[hh][1][0], 0,0,0);
      macc[hh][1][1] = __builtin_amdgcn_mfma_f32_16x16x32_bf16(a1, b1, macc[hh][1][1], 0,0,0);
    }
  }
  // ELU -> hs (bf16, in LDS)
  #pragma unroll
  for(int hh=0; hh<2; hh++){
    int h = w*2 + hh;
    #pragma unroll
    for(int mt=0; mt<2; mt++){
      #pragma unroll
      for(int nt=0; nt<2; nt++){
        #pragma unroll
        for(int reg=0; reg<4; reg++){
          int row = mt*16 + quad*4 + reg;
          float v = macc[hh][mt][nt][reg];
          v = (v > 0.f) ? v : expm1f(v);
          hs[row*VSP + h*32 + nt*16 + l16] = f2bf(v);
        }
      }
    }
  }
  __syncthreads();

  // ---- stage 2: Wa MFMA + residual + classifier + log_softmax ----
  f32x4 acc[2][4];
  #pragma unroll
  for(int mt=0;mt<2;mt++)
    #pragma unroll
    for(int nt=0;nt<4;nt++) acc[mt][nt]=(f32x4)(0.f);
  const u16* wap = Wta + (size_t)t*65536;
  #pragma unroll
  for(int kk=0; kk<8; kk++){
    int kb = kk*32 + quad*8;
    bf16x8 a0 = *(const bf16x8*)(hs + l16*VSP + kb);
    bf16x8 a1 = *(const bf16x8*)(hs + (16+l16)*VSP + kb);
    #pragma unroll
    for(int nt=0; nt<4; nt++){
      int n = w*64 + nt*16 + l16;
      bf16x8 b = *(const bf16x8*)(wap + (size_t)n*DD + kb);
      acc[0][nt] = __builtin_amdgcn_mfma_f32_16x16x32_bf16(a0, b, acc[0][nt], 0,0,0);
      acc[1][nt] = __builtin_amdgcn_mfma_f32_16x16x32_bf16(a1, b, acc[1][nt], 0,0,0);
    }
  }
  #pragma unroll
  for(int nt=0; nt<4; nt++){
    int colg = w*64 + nt*16 + l16;
    float bav = ba[t*DD + colg];
    #pragma unroll
    for(int mt=0; mt<2; mt++){
      #pragma unroll
      for(int reg=0; reg<4; reg++){
        int row = mt*16 + quad*4 + reg;
        int g = gids[row];
        float xr = (g>=0) ? bf2f(xb[(size_t)g*DD + colg]) : 0.f;
        h2s[row*VSP + colg] = f2bf(acc[mt][nt][reg] + bav + xr);
      }
    }
  }
  __syncthreads();
  if(w < 2){
    f32x4 cacc = (f32x4)(0.f);
    #pragma unroll
    for(int kk=0; kk<8; kk++){
      int kb = kk*32 + quad*8;
      bf16x8 a = *(const bf16x8*)(h2s + (w*16 + l16)*VSP + kb);
      bf16x8 b = *(const bf16x8*)(Wot + (size_t)l16*DD + kb);
      cacc = __builtin_amdgcn_mfma_f32_16x16x32_bf16(a, b, cacc, 0,0,0);
    }
    float bov = bo[l16];
    #pragma unroll
    for(int reg=0; reg<4; reg++){
      int row = w*16 + quad*4 + reg;
      int g = gids[row];
      float v = cacc[reg] + bov;     // col = l16 = class
      float m = v;
      m = fmaxf(m, __shfl_xor(m,1)); m = fmaxf(m, __shfl_xor(m,2));
      m = fmaxf(m, __shfl_xor(m,4)); m = fmaxf(m, __shfl_xor(m,8));
      float p = __expf(v - m);
      p += __shfl_xor(p,1); p += __shfl_xor(p,2);
      p += __shfl_xor(p,4); p += __shfl_xor(p,8);
      float lse = m + __logf(p);
      if(g >= 0) out[(size_t)g*NC + l16] = v - lse;
    }
  }
}

extern "C" void kernel_launch(void* const* d_in, const int* in_sizes, int n_in,
                              void* d_out, int out_size, void* d_ws, size_t ws_size,
                              hipStream_t stream)
{
  const float* x     = (const float*)d_in[0];
  const int*   ei    = (const int*)d_in[1];
  const int*   ntype = (const int*)d_in[2];
  const int*   etype = (const int*)d_in[3];
  const float* Wk    = (const float*)d_in[4];
  const float* bk    = (const float*)d_in[5];
  const float* Wq    = (const float*)d_in[6];
  const float* bq    = (const float*)d_in[7];
  const float* Wv    = (const float*)d_in[8];
  const float* bv    = (const float*)d_in[9];
  const float* Wa    = (const float*)d_in[10];
  const float* ba    = (const float*)d_in[11];
  const float* prior = (const float*)d_in[12];
  const float* ratt  = (const float*)d_in[13];
  const float* rmsg  = (const float*)d_in[14];
  const float* Wo    = (const float*)d_in[15];
  const float* bo    = (const float*)d_in[16];
  float* out = (float*)d_out;

  char* ws = (char*)d_ws;
  int* iw      = (int*)ws;
  int* cnt     = iw + 0;
  int* bcur    = iw + 4;
  int* boff    = iw + 8;
  int* off2    = iw + 16;                 // NN*NR+1 = 100001 ints
  int* perm    = iw + 100032;             // 20096 ints
  int* packed  = iw + 120128;             // NE ints (ends 440128)
  int* bsum    = iw + 440128;             // 512 ints (ends 440640, unused now)
  int* pos2    = iw + 440640;             // NN ints (ends 460640)
  u64* lb      = (u64*)(iw + 460640);     // NBS u64 lookback slots (ends 460836; 8B-aligned)

  size_t fb = 1843456;                    // 460836*4 = 1843344, 256-aligned up
  unsigned char* KVn = (unsigned char*)(ws + fb); fb += 768ull*NPAD;  // 15.43 MB (fp8 K + bf16 V)
  u16*   Qn    = (u16*)(ws + fb);   fb += 2ull*NPAD*DD;         // 10.29 MB (perm order)
  u16*   QA    = (u16*)(ws + fb);   fb += 2ull*NPAD*NR*DD;      // 51.45 MB (perm order)
  u16*   aggrV = (u16*)(ws + fb);   fb += 2ull*NPAD*NR*DD;      // 51.45 MB (perm order)
  u16*   xb    = (u16*)(ws + fb);   fb += 2ull*NN*DD;           // 10.24 MB (dedicated: k_mo residual)
  u16*   Wtk   = (u16*)(ws + fb);   fb += 2ull*3*65536;
  u16*   Wtq   = (u16*)(ws + fb);   fb += 2ull*3*65536;
  u16*   Wtv   = (u16*)(ws + fb);   fb += 2ull*3*65536;
  u16*   Wta   = (u16*)(ws + fb);   fb += 2ull*3*65536;
  u16*   Wot   = (u16*)(ws + fb);   fb += 2ull*NC*DD;
  u16*   Mtm   = (u16*)(ws + fb);   fb += 2ull*NR*NH*KK*KK;
  u16*   Atb   = (u16*)(ws + fb);   fb += 2ull*NR*NH*KK*KK;
  // total ~142 MB (validated high-water mark: 165.6 MB)

  hipMemsetAsync(iw, 0, (size_t)(16 + NN*NR + 1)*sizeof(int), stream); // cnt,bcur,boff,off2
  hipMemsetAsync(lb, 0, (size_t)NBS*sizeof(u64), stream);              // lookback slots

  k_pre1   <<<1408, 256, 0, stream>>>(ntype, ei, etype, cnt, off2, perm);
  k_scan   <<<NBS+79, 256, 0, stream>>>(off2, lb, cnt, ntype, bcur, perm, pos2, boff);
  k_work1  <<<4854, 256, 0, stream>>>(ei, etype, off2, packed, pos2, x, xb,
                                      Wk, Wq, Wv, Wa, Wtk, Wtq, Wtv, Wta,
                                      rmsg, ratt, prior, Wo, Mtm, Atb, Wot);
  k_projqa <<<1256, 256, 0, stream>>>(xb, perm, boff, Wtk, Wtq, Wtv, bk, bq, bv,
                                      KVn, Qn);
  k_qa     <<<628*NR, 256, 0, stream>>>(Qn, Atb, QA);
  k_edge   <<<5024, 256, 0, stream>>>(KVn, QA, off2, packed, perm, aggrV);
  k_mo     <<<628, 256, 0, stream>>>(aggrV, Mtm, xb, perm, boff, Wta, ba, Wot, bo, out);
}

// Round 8
// 285.864 us; speedup vs baseline: 1.0648x; 1.0483x over previous
//
#include <hip/hip_runtime.h>
#include <hip/hip_bf16.h>
#include <math.h>

#define NN 20000
#define NE 320000
#define DD 256
#define NH 8
#define KK 32
#define NR 5
#define NC 16
#define NPAD 20096  // perm-padded row count (boff 32-aligned, 3 types)
#define EPB 1024    // scan elements per block
#define NBS 98      // ceil(NN*NR / EPB)

typedef unsigned short u16;
typedef unsigned int u32;
typedef unsigned long long u64;
typedef __attribute__((ext_vector_type(8))) short bf16x8;
typedef __attribute__((ext_vector_type(4))) float f32x4;

__device__ __forceinline__ float bf2f(u16 v){ return __uint_as_float(((u32)v)<<16); }
__device__ __forceinline__ u16 f2bf(float f){
  u32 u = __float_as_uint(f);
  return (u16)((u + 0x7FFFu + ((u>>16)&1u)) >> 16);
}
// OCP e4m3fn software encode (RNE). |f| << 448 here (K projections ~ N(0,1)).
__device__ __forceinline__ unsigned char f2fp8(float f){
  u32 b = __float_as_uint(f * 0x1.0p-120f);   // e4m3 exp/mant now at bits 26..20
  u32 s = (b >> 24) & 0x80u;
  u32 m = b & 0x7fffffffu;
  u32 r = m + 0x7FFFFu + ((m >> 20) & 1u);    // RNE at bit 20
  return (unsigned char)(s | ((r >> 20) & 0x7fu));
}
// decode (value scaled by 2^-120; the 2^120 is pre-folded into q registers)
#define FP8D(t) __uint_as_float((((t)&0x80u)<<24) | (((t)&0x7fu)<<20))

struct u96 { u32 x, y, z; };   // 12B, align 4 (dwordx3-friendly)

// ---------------- pre1: nb_count + deg + perm=-1 init (independent block ranges) --------
__global__ void k_pre1(const int* __restrict__ ntype, const int* __restrict__ ei,
                       const int* __restrict__ etype, int* __restrict__ cnt,
                       int* __restrict__ off2, int* __restrict__ perm){
  int b = blockIdx.x;
  if(b < 79){
    int n = b*256 + threadIdx.x;
    int t = (n < NN) ? ntype[n] : -1;
    int lane = threadIdx.x & 63;
    #pragma unroll
    for(int tt=0; tt<3; tt++){
      unsigned long long mask = __ballot(t == tt);
      int leader = __ffsll((long long)mask) - 1;
      if(lane == leader) atomicAdd(&cnt[tt], __popcll(mask));
    }
  } else if(b < 1329){
    int e = (b-79)*256 + threadIdx.x;
    if(e < NE) atomicAdd(&off2[ei[NE + e]*NR + etype[e]], 1);
  } else {
    int i = (b-1329)*256 + threadIdx.x;
    if(i < NPAD) perm[i] = -1;
  }
}

// ---------------- k_scan: ONE-kernel decoupled-lookback exclusive scan + nb_scatter -----
__global__ __launch_bounds__(256) void k_scan(
    int* __restrict__ off2, u64* __restrict__ lb,
    const int* __restrict__ cnt, const int* __restrict__ ntype,
    int* __restrict__ bcur, int* __restrict__ perm,
    int* __restrict__ pos2, int* __restrict__ boff)
{
  int b = blockIdx.x;
  if(b < NBS){
    __shared__ int sh[256];
    __shared__ int exoff_s;
    int t = threadIdx.x;
    int base = b*EPB + t*4;
    int4 v = make_int4(0,0,0,0);
    if(base < NN*NR) v = *(const int4*)(off2 + base);
    int ts = v.x + v.y + v.z + v.w;
    sh[t] = ts;
    __syncthreads();
    for(int off=1; off<256; off<<=1){
      int val = (t >= off) ? sh[t-off] : 0;
      __syncthreads();
      sh[t] += val;
      __syncthreads();
    }
    int btot = sh[255];
    if(t == 0){
      if(b == 0){
        atomicExch(&lb[0], (2ull<<32) | (u32)btot);
        exoff_s = 0;
      } else {
        atomicExch(&lb[b], (1ull<<32) | (u32)btot);
        int sum = 0, j = b-1;
        while(true){
          u64 s = atomicAdd(&lb[j], 0ull);    // device-scope read
          u32 st = (u32)(s >> 32);
          if(st == 0) continue;               // predecessor not published yet
          sum += (int)(u32)s;
          if(st == 2) break;                  // hit an inclusive prefix
          --j;
        }
        atomicExch(&lb[b], (2ull<<32) | (u32)(sum + btot));
        exoff_s = sum;
      }
    }
    __syncthreads();
    int ex = exoff_s + sh[t] - ts;            // global exclusive before this thread's 4
    if(base < NN*NR){
      int4 o;
      o.x = ex; o.y = ex + v.x; o.z = ex + v.x + v.y; o.w = ex + v.x + v.y + v.z;
      *(int4*)(off2 + base) = o;
    }
  } else {
    int a32 = (cnt[0]+31)&~31;
    int b32 = (cnt[1]+31)&~31;
    if(b == NBS && threadIdx.x == 0){ boff[0]=0; boff[1]=a32; boff[2]=a32+b32; }
    int boffl[3] = {0, a32, a32 + b32};
    int n = (b - NBS)*256 + threadIdx.x;
    int t = (n < NN) ? ntype[n] : -1;
    int lane = threadIdx.x & 63;
    #pragma unroll
    for(int tt=0; tt<3; tt++){
      unsigned long long mask = __ballot(t == tt);
      if(t == tt){
        int rank = __popcll(mask & ((1ull<<lane)-1ull));
        int leader = __ffsll((long long)mask) - 1;
        int base2 = 0;
        if(lane == leader) base2 = atomicAdd(&bcur[tt], __popcll(mask));
        base2 = __shfl(base2, leader);
        int p = boffl[tt] + base2 + rank;
        perm[p] = n;
        pos2[n] = p;               // inverse perm: KVn/QA/aggrV all perm-ordered
      }
    }
  }
}

// ---------------- work1: escatter + castx + castw + castsmall (independent ranges) ------
__global__ __launch_bounds__(256) void k_work1(
    const int* __restrict__ ei, const int* __restrict__ etype,
    int* __restrict__ off2, int* __restrict__ packed,
    const int* __restrict__ pos2,
    const float* __restrict__ x, u16* __restrict__ xb,
    const float* __restrict__ Wk, const float* __restrict__ Wq,
    const float* __restrict__ Wv, const float* __restrict__ Wa,
    u16* __restrict__ Wtk, u16* __restrict__ Wtq,
    u16* __restrict__ Wtv, u16* __restrict__ Wta,
    const float* __restrict__ rmsg, const float* __restrict__ ratt,
    const float* __restrict__ prior, const float* __restrict__ Wo,
    u16* __restrict__ Mtm, u16* __restrict__ Atb, u16* __restrict__ Wot)
{
  __shared__ float tile[32][33];
  int b = blockIdx.x;
  if(b < 1250){
    int e = b*256 + threadIdx.x;
    if(e < NE){
      int pos = atomicAdd(&off2[ei[NE+e]*NR + etype[e]], 1);
      packed[pos] = pos2[ei[e]];
    }
  } else if(b < 3750){
    int i = (b-1250)*256 + threadIdx.x;     // castx: 8 floats per thread
    float4 v0 = ((const float4*)x)[i*2+0];
    float4 v1 = ((const float4*)x)[i*2+1];
    uint4 o;
    o.x = (u32)f2bf(v0.x) | ((u32)f2bf(v0.y)<<16);
    o.y = (u32)f2bf(v0.z) | ((u32)f2bf(v0.w)<<16);
    o.z = (u32)f2bf(v1.x) | ((u32)f2bf(v1.y)<<16);
    o.w = (u32)f2bf(v1.z) | ((u32)f2bf(v1.w)<<16);
    ((uint4*)xb)[i] = o;
  } else if(b < 4518){
    int bp = b - 3750;                      // castw: 768 tiles = 8 x 8 x 12
    int bx = bp & 7, by = (bp>>3) & 7, z = bp >> 6;
    int tensor = z/3, t = z%3;
    const float* W = (tensor==0) ? Wk : (tensor==1) ? Wq : (tensor==2) ? Wv : Wa;
    u16* O = (tensor==0) ? Wtk : (tensor==1) ? Wtq : (tensor==2) ? Wtv : Wta;
    int i0 = bx*32, j0 = by*32;
    int rr = threadIdx.x>>5, cc = threadIdx.x&31;
    #pragma unroll
    for(int p=0;p<4;p++)
      tile[rr+p*8][cc] = W[t*65536 + (i0+rr+p*8)*256 + j0+cc];
    __syncthreads();
    #pragma unroll
    for(int p=0;p<4;p++)
      O[t*65536 + (j0+rr+p*8)*256 + i0+cc] = f2bf(tile[cc][rr+p*8]);
  } else {
    int bp = b - 4518;                      // castsmall: 336 blocks
    if(bp < 160){
      int idx = bp*256 + threadIdx.x;       // rel_msg transpose: [r,h,k,l] -> [r,h,l,k]
      int l = idx & 31, k = (idx >> 5) & 31, rh = idx >> 10;
      Mtm[(rh*32 + l)*32 + k] = f2bf(rmsg[idx]);
    } else if(bp < 320){
      int idx = (bp-160)*256 + threadIdx.x; // rel_att cast w/ prior/sqrtK folded
      int rh = idx >> 10;
      float scale = prior[rh] * 0.17677669529663687f;  // 1/sqrt(32)
      Atb[idx] = f2bf(ratt[idx] * scale);
    } else {
      int idx = (bp-320)*256 + threadIdx.x; // W_out transpose: [k,c] -> [c,k]
      int c = idx & 15, k = idx >> 4;
      Wot[c*DD + k] = f2bf(Wo[k*NC + c]);
    }
  }
}

// ---------------- FUSED typed K/Q/V projections + QA bilinear --------
// KVn rows 768B: per 4-dim group g: [K 4x fp8e4m3][V 4x bf16] at byte g*12.
// QA bilinear folded back in (k_qa kernel + Qn buffer eliminated): after the Q LDS
// stage, wave w = head (cb>>5)+w computes QA_r = Q x Atb[r] via MFMA and stores the
// accumulator DIRECTLY to global (perm-ordered, u16) — zero extra barriers, values
// bit-identical to the old k_qa path.
#define XSP 264   // padded row (u16) for x-tile / Q stages
#define KSP 784   // padded row (bytes) for KV stage (768 + 16)
__global__ __launch_bounds__(256) void k_projqa(
    const u16* __restrict__ xb, const int* __restrict__ perm, const int* __restrict__ boff,
    const u16* __restrict__ Wtk, const u16* __restrict__ Wtq, const u16* __restrict__ Wtv,
    const float* __restrict__ bk, const float* __restrict__ bq, const float* __restrict__ bv,
    const u16* __restrict__ Atb,
    unsigned char* __restrict__ KVn, u16* __restrict__ QA)
{
  __shared__ unsigned char smemb[32*KSP];   // x-tile (u16 view) -> KV-stage (bytes) -> Q-stage
  __shared__ int gids[32];
  u16* smem = (u16*)smemb;
  int tid = threadIdx.x;
  int ts = (blockIdx.x >> 1)*32;
  int cb = (blockIdx.x & 1)*128;          // column base for this block
  int t = (ts >= boff[2]) ? 2 : (ts >= boff[1]) ? 1 : 0;   // boff 32-aligned
  if(tid < 32) gids[tid] = perm[ts + tid];
  __syncthreads();
  #pragma unroll
  for(int it=0; it<4; it++){
    int q = tid + it*256;
    int row = q >> 5, c = q & 31;
    int g = gids[row];
    uint4 v = make_uint4(0,0,0,0);
    if(g >= 0) v = ((const uint4*)(xb + (size_t)g*DD))[c];
    ((uint4*)(smem + row*XSP))[c] = v;
  }
  __syncthreads();
  int lane = tid & 63;
  int w = tid >> 6;
  int quad = lane >> 4;
  int l16 = lane & 15;
  f32x4 accK[2][2], accQ[2][2], accV[2][2];   // [mt][nt]
  #pragma unroll
  for(int mt=0;mt<2;mt++)
    #pragma unroll
    for(int nt=0;nt<2;nt++){
      accK[mt][nt]=(f32x4)(0.f); accQ[mt][nt]=(f32x4)(0.f); accV[mt][nt]=(f32x4)(0.f);
    }
  const u16* wkp = Wtk + (size_t)t*65536;
  const u16* wqp = Wtq + (size_t)t*65536;
  const u16* wvp = Wtv + (size_t)t*65536;
  #pragma unroll
  for(int kk=0; kk<8; kk++){
    int kb = kk*32 + quad*8;
    bf16x8 a0 = *(const bf16x8*)(smem + l16*XSP + kb);
    bf16x8 a1 = *(const bf16x8*)(smem + (16+l16)*XSP + kb);
    #pragma unroll
    for(int nt=0; nt<2; nt++){
      int n = cb + w*32 + nt*16 + l16;
      bf16x8 bK = *(const bf16x8*)(wkp + (size_t)n*DD + kb);
      bf16x8 bQ = *(const bf16x8*)(wqp + (size_t)n*DD + kb);
      bf16x8 bV = *(const bf16x8*)(wvp + (size_t)n*DD + kb);
      accK[0][nt] = __builtin_amdgcn_mfma_f32_16x16x32_bf16(a0, bK, accK[0][nt], 0,0,0);
      accK[1][nt] = __builtin_amdgcn_mfma_f32_16x16x32_bf16(a1, bK, accK[1][nt], 0,0,0);
      accQ[0][nt] = __builtin_amdgcn_mfma_f32_16x16x32_bf16(a0, bQ, accQ[0][nt], 0,0,0);
      accQ[1][nt] = __builtin_amdgcn_mfma_f32_16x16x32_bf16(a1, bQ, accQ[1][nt], 0,0,0);
      accV[0][nt] = __builtin_amdgcn_mfma_f32_16x16x32_bf16(a0, bV, accV[0][nt], 0,0,0);
      accV[1][nt] = __builtin_amdgcn_mfma_f32_16x16x32_bf16(a1, bV, accV[1][nt], 0,0,0);
    }
  }
  __syncthreads();                 // x-tile dead; reuse smemb as KV stage (768B rows)
  #pragma unroll
  for(int nt=0; nt<2; nt++){
    int lc = w*32 + nt*16 + l16;   // local col 0..127
    int colg = cb + lc;
    int g12 = (colg >> 2)*12, j = colg & 3;
    float bkv = bk[t*DD+colg], bvv = bv[t*DD+colg];
    #pragma unroll
    for(int mt=0; mt<2; mt++){
      #pragma unroll
      for(int reg=0; reg<4; reg++){
        int row = mt*16 + quad*4 + reg;
        smemb[row*KSP + g12 + j] = f2fp8(accK[mt][nt][reg] + bkv);
        *(u16*)(smemb + row*KSP + g12 + 4 + j*2) = f2bf(accV[mt][nt][reg] + bvv);
      }
    }
  }
  __syncthreads();
  {                                // KV store: 32 rows x 384B (this half) = 768 uint4
    int cbs = (cb >> 2)*12;        // 0 or 384
    #pragma unroll
    for(int it=0; it<3; it++){
      int qq = tid + it*256;
      int row = qq / 24, c = qq - row*24;
      *(uint4*)(KVn + (size_t)(ts+row)*768 + cbs + c*16) =
          *(const uint4*)(smemb + row*KSP + cbs + c*16);
    }
  }
  __syncthreads();                 // KV stage dead; reuse smem as Q stage (bf16)
  #pragma unroll
  for(int nt=0; nt<2; nt++){
    int lc = w*32 + nt*16 + l16;
    float bqv = bq[t*DD + cb + lc];
    #pragma unroll
    for(int mt=0; mt<2; mt++){
      #pragma unroll
      for(int reg=0; reg<4; reg++){
        int row = mt*16 + quad*4 + reg;
        smem[row*XSP + lc] = f2bf(accQ[mt][nt][reg] + bqv);
      }
    }
  }
  __syncthreads();
  // ---- QA tail: wave w = head (cb>>5)+w; register->global stores, no barriers ----
  {
    int h = (cb >> 5) + w;
    bf16x8 qf0 = *(const bf16x8*)(smem + l16*XSP + w*32 + quad*8);
    bf16x8 qf1 = *(const bf16x8*)(smem + (16+l16)*XSP + w*32 + quad*8);
    for(int r=0; r<NR; r++){
      f32x4 acc[2][2];   // [mt][nt]
      #pragma unroll
      for(int mt=0;mt<2;mt++)
        #pragma unroll
        for(int nt=0;nt<2;nt++) acc[mt][nt]=(f32x4)(0.f);
      const u16* ap = Atb + (size_t)(r*NH + h)*1024;
      bf16x8 b0 = *(const bf16x8*)(ap + l16*32 + quad*8);
      bf16x8 b1 = *(const bf16x8*)(ap + (16+l16)*32 + quad*8);
      acc[0][0] = __builtin_amdgcn_mfma_f32_16x16x32_bf16(qf0, b0, acc[0][0], 0,0,0);
      acc[0][1] = __builtin_amdgcn_mfma_f32_16x16x32_bf16(qf0, b1, acc[0][1], 0,0,0);
      acc[1][0] = __builtin_amdgcn_mfma_f32_16x16x32_bf16(qf1, b0, acc[1][0], 0,0,0);
      acc[1][1] = __builtin_amdgcn_mfma_f32_16x16x32_bf16(qf1, b1, acc[1][1], 0,0,0);
      #pragma unroll
      for(int mt=0; mt<2; mt++)
        #pragma unroll
        for(int nt=0; nt<2; nt++)
          #pragma unroll
          for(int reg=0; reg<4; reg++){
            int row = mt*16 + quad*4 + reg;
            QA[((size_t)(ts+row)*NR + r)*DD + cb + w*32 + nt*16 + l16] =
                f2bf(acc[mt][nt][reg]);
          }
    }
  }
}

// ---------------- fused per-node softmax + aggregation: r-sorted, batched gathers ----------
// Barrier-free, 4 nodes/block, 1 wave/node. KV rows 768B (fp8 K + bf16 V);
// lane loads 12B at lane*12 (dwordx3). The 2^120 fp8-decode scale is folded into q.
__global__ __launch_bounds__(256) void k_edge(
    const unsigned char* __restrict__ KVn, const u16* __restrict__ QA,
    const int* __restrict__ off2, const int* __restrict__ packed,
    const int* __restrict__ perm, u16* __restrict__ aggrV)
{
  int lane = threadIdx.x & 63;
  int p = blockIdx.x*4 + (threadIdx.x >> 6);
  if(p >= NPAD) return;
  int n = perm[p];
  if(n < 0) return;
  int off = lane*4;                  // = h*32 + j*4 with h=lane>>3
  float4 qa[NR];
  {
    const u16* qp = QA + (size_t)p*NR*DD + off;
    const float SC = 0x1.0p120f;     // folds fp8 decode scale; exact (power of 2)
    #pragma unroll
    for(int r=0;r<NR;r++){
      ushort4 q = *(const ushort4*)(qp + r*DD);
      qa[r] = make_float4(bf2f(q.x)*SC,bf2f(q.y)*SC,bf2f(q.z)*SC,bf2f(q.w)*SC);
    }
  }
  int eb[NR+1];
  eb[0] = (n==0) ? 0 : off2[n*NR - 1];
  #pragma unroll
  for(int i=1;i<=NR;i++) eb[i] = off2[n*NR + i - 1];
  float4 acc[NR];
  float s = 0.f;
  int lo12 = lane*12;

  #define EDGE_DOT(kv, q, dd) \
    { u32 _kx = (kv).x; \
      dd = FP8D(_kx & 0xffu)*(q).x + FP8D((_kx>>8) & 0xffu)*(q).y \
         + FP8D((_kx>>16) & 0xffu)*(q).z + FP8D(_kx>>24)*(q).w; }
  #define EDGE_ACC(kv, p, a) \
    { float v0=__uint_as_float((kv).y<<16), v1=__uint_as_float((kv).y&0xffff0000u); \
      float v2=__uint_as_float((kv).z<<16), v3=__uint_as_float((kv).z&0xffff0000u); \
      (a).x += (p)*v0; (a).y += (p)*v1; (a).z += (p)*v2; (a).w += (p)*v3; }
  #define RED3(d) { d += __shfl_xor(d,1); d += __shfl_xor(d,2); d += __shfl_xor(d,4); }

  #pragma unroll
  for(int r=0;r<NR;r++){
    float4 q = qa[r];
    float4 a = make_float4(0.f,0.f,0.f,0.f);
    int e = eb[r], end = eb[r+1];
    for(; e+4 <= end; e += 4){
      int s0 = packed[e], s1 = packed[e+1], s2 = packed[e+2], s3 = packed[e+3];
      u96 kv0 = *(const u96*)(KVn + (size_t)s0*768 + lo12);
      u96 kv1 = *(const u96*)(KVn + (size_t)s1*768 + lo12);
      u96 kv2 = *(const u96*)(KVn + (size_t)s2*768 + lo12);
      u96 kv3 = *(const u96*)(KVn + (size_t)s3*768 + lo12);
      float d0,d1,d2,d3;
      EDGE_DOT(kv0,q,d0); EDGE_DOT(kv1,q,d1); EDGE_DOT(kv2,q,d2); EDGE_DOT(kv3,q,d3);
      RED3(d0); RED3(d1); RED3(d2); RED3(d3);
      float p0=__expf(d0), p1=__expf(d1), p2=__expf(d2), p3=__expf(d3);
      s += p0 + p1 + p2 + p3;
      EDGE_ACC(kv0,p0,a); EDGE_ACC(kv1,p1,a); EDGE_ACC(kv2,p2,a); EDGE_ACC(kv3,p3,a);
    }
    if(e+2 <= end){
      int s0 = packed[e], s1 = packed[e+1];
      u96 kv0 = *(const u96*)(KVn + (size_t)s0*768 + lo12);
      u96 kv1 = *(const u96*)(KVn + (size_t)s1*768 + lo12);
      float d0,d1;
      EDGE_DOT(kv0,q,d0); EDGE_DOT(kv1,q,d1);
      RED3(d0); RED3(d1);
      float p0=__expf(d0), p1=__expf(d1);
      s += p0 + p1;
      EDGE_ACC(kv0,p0,a); EDGE_ACC(kv1,p1,a);
      e += 2;
    }
    if(e < end){
      int s0 = packed[e];
      u96 kv0 = *(const u96*)(KVn + (size_t)s0*768 + lo12);
      float d0;
      EDGE_DOT(kv0,q,d0);
      RED3(d0);
      float p0=__expf(d0);
      s += p0;
      EDGE_ACC(kv0,p0,a);
    }
    acc[r] = a;
  }
  #undef EDGE_DOT
  #undef EDGE_ACC
  #undef RED3
  float inv = (s > 0.f) ? (1.f/s) : 0.f;
  u16* op = aggrV + (size_t)p*NR*DD + off;
  #pragma unroll
  for(int r=0;r<NR;r++){
    ushort4 o;
    o.x=f2bf(acc[r].x*inv); o.y=f2bf(acc[r].y*inv);
    o.z=f2bf(acc[r].z*inv); o.w=f2bf(acc[r].w*inv);
    *(ushort4*)(op + r*DD) = o;
  }
}

// ---------------- FUSED k_msg + k_out (aggrV perm-ordered; stage-1 double-buffered) ------
// Residual read from xb (bf16): halves the gathered x stream (re-quantized right after add).
#define VSP 264
__global__ __launch_bounds__(256) void k_mo(
    const u16* __restrict__ aggrV, const u16* __restrict__ Mtm,
    const u16* __restrict__ xb,
    const int* __restrict__ perm, const int* __restrict__ boff,
    const u16* __restrict__ Wta, const float* __restrict__ ba,
    const u16* __restrict__ Wot, const float* __restrict__ bo,
    float* __restrict__ out)
{
  __shared__ u16 Vs[32*VSP];
  __shared__ u16 hs[32*VSP];
  __shared__ u16 h2s[32*VSP];
  __shared__ int gids[32];
  int tid = threadIdx.x;
  int ts = blockIdx.x*32;
  int t = (ts >= boff[2]) ? 2 : (ts >= boff[1]) ? 1 : 0;
  if(tid < 32) gids[tid] = perm[ts + tid];
  __syncthreads();
  int lane = tid & 63, w = tid >> 6, quad = lane >> 4, l16 = lane & 15;

  // ---- stage 1: rel_msg MFMA over r, double-buffered (Vs / h2s) ----
  f32x4 macc[2][2][2];
  #pragma unroll
  for(int hh=0;hh<2;hh++)
    #pragma unroll
    for(int mt=0;mt<2;mt++)
      #pragma unroll
      for(int nt=0;nt<2;nt++) macc[hh][mt][nt]=(f32x4)(0.f);
  #pragma unroll
  for(int r=0;r<NR;r++){
    u16* B = (r & 1) ? h2s : Vs;
    #pragma unroll
    for(int it=0; it<4; it++){
      int q = tid + it*256;
      int row = q >> 5, c = q & 31;
      ((uint4*)(B + row*VSP))[c] =
        ((const uint4*)(aggrV + ((size_t)(ts+row)*NR + r)*DD))[c];
    }
    __syncthreads();   // single barrier: prior buffer's reads retired before next overwrite
    #pragma unroll
    for(int hh=0; hh<2; hh++){
      int h = w*2 + hh;
      bf16x8 a0 = *(const bf16x8*)(B + l16*VSP + h*32 + quad*8);
      bf16x8 a1 = *(const bf16x8*)(B + (16+l16)*VSP + h*32 + quad*8);
      const u16* mp = Mtm + ((size_t)(r*NH + h)*32)*32;
      bf16x8 b0 = *(const bf16x8*)(mp + l16*32 + quad*8);
      bf16x8 b1 = *(const bf16x8*)(mp + (16+l16)*32 + quad*8);
      macc[hh][0][0] = __builtin_amdgcn_mfma_f32_16x16x32_bf16(a0, b0, macc[hh][0][0], 0,0,0);
      macc[hh][0][1] = __builtin_amdgcn_mfma_f32_16x16x32_bf16(a0, b1, macc[hh][0][1], 0,0,0);
      macc[hh][1][0] = __builtin_amdgcn_mfma_f32_16x16x32_bf16(a1, b0, macc[hh][1][0], 0,0,0);
      macc[hh][1][1] = __builtin_amdgcn_mfma_f32_16x16x32_bf16(a1, b1, macc[hh][1][1], 0,0,0);
    }
  }
  // ELU -> hs (bf16, in LDS)
  #pragma unroll
  for(int hh=0; hh<2; hh++){
    int h = w*2 + hh;
    #pragma unroll
    for(int mt=0; mt<2; mt++){
      #pragma unroll
      for(int nt=0; nt<2; nt++){
        #pragma unroll
        for(int reg=0; reg<4; reg++){
          int row = mt*16 + quad*4 + reg;
          float v = macc[hh][mt][nt][reg];
          v = (v > 0.f) ? v : expm1f(v);
          hs[row*VSP + h*32 + nt*16 + l16] = f2bf(v);
        }
      }
    }
  }
  __syncthreads();

  // ---- stage 2: Wa MFMA + residual + classifier + log_softmax ----
  f32x4 acc[2][4];
  #pragma unroll
  for(int mt=0;mt<2;mt++)
    #pragma unroll
    for(int nt=0;nt<4;nt++) acc[mt][nt]=(f32x4)(0.f);
  const u16* wap = Wta + (size_t)t*65536;
  #pragma unroll
  for(int kk=0; kk<8; kk++){
    int kb = kk*32 + quad*8;
    bf16x8 a0 = *(const bf16x8*)(hs + l16*VSP + kb);
    bf16x8 a1 = *(const bf16x8*)(hs + (16+l16)*VSP + kb);
    #pragma unroll
    for(int nt=0; nt<4; nt++){
      int n = w*64 + nt*16 + l16;
      bf16x8 b = *(const bf16x8*)(wap + (size_t)n*DD + kb);
      acc[0][nt] = __builtin_amdgcn_mfma_f32_16x16x32_bf16(a0, b, acc[0][nt], 0,0,0);
      acc[1][nt] = __builtin_amdgcn_mfma_f32_16x16x32_bf16(a1, b, acc[1][nt], 0,0,0);
    }
  }
  #pragma unroll
  for(int nt=0; nt<4; nt++){
    int colg = w*64 + nt*16 + l16;
    float bav = ba[t*DD + colg];
    #pragma unroll
    for(int mt=0; mt<2; mt++){
      #pragma unroll
      for(int reg=0; reg<4; reg++){
        int row = mt*16 + quad*4 + reg;
        int g = gids[row];
        float xr = (g>=0) ? bf2f(xb[(size_t)g*DD + colg]) : 0.f;
        h2s[row*VSP + colg] = f2bf(acc[mt][nt][reg] + bav + xr);
      }
    }
  }
  __syncthreads();
  if(w < 2){
    f32x4 cacc = (f32x4)(0.f);
    #pragma unroll
    for(int kk=0; kk<8; kk++){
      int kb = kk*32 + quad*8;
      bf16x8 a = *(const bf16x8*)(h2s + (w*16 + l16)*VSP + kb);
      bf16x8 b = *(const bf16x8*)(Wot + (size_t)l16*DD + kb);
      cacc = __builtin_amdgcn_mfma_f32_16x16x32_bf16(a, b, cacc, 0,0,0);
    }
    float bov = bo[l16];
    #pragma unroll
    for(int reg=0; reg<4; reg++){
      int row = w*16 + quad*4 + reg;
      int g = gids[row];
      float v = cacc[reg] + bov;     // col = l16 = class
      float m = v;
      m = fmaxf(m, __shfl_xor(m,1)); m = fmaxf(m, __shfl_xor(m,2));
      m = fmaxf(m, __shfl_xor(m,4)); m = fmaxf(m, __shfl_xor(m,8));
      float p = __expf(v - m);
      p += __shfl_xor(p,1); p += __shfl_xor(p,2);
      p += __shfl_xor(p,4); p += __shfl_xor(p,8);
      float lse = m + __logf(p);
      if(g >= 0) out[(size_t)g*NC + l16] = v - lse;
    }
  }
}

extern "C" void kernel_launch(void* const* d_in, const int* in_sizes, int n_in,
                              void* d_out, int out_size, void* d_ws, size_t ws_size,
                              hipStream_t stream)
{
  const float* x     = (const float*)d_in[0];
  const int*   ei    = (const int*)d_in[1];
  const int*   ntype = (const int*)d_in[2];
  const int*   etype = (const int*)d_in[3];
  const float* Wk    = (const float*)d_in[4];
  const float* bk    = (const float*)d_in[5];
  const float* Wq    = (const float*)d_in[6];
  const float* bq    = (const float*)d_in[7];
  const float* Wv    = (const float*)d_in[8];
  const float* bv    = (const float*)d_in[9];
  const float* Wa    = (const float*)d_in[10];
  const float* ba    = (const float*)d_in[11];
  const float* prior = (const float*)d_in[12];
  const float* ratt  = (const float*)d_in[13];
  const float* rmsg  = (const float*)d_in[14];
  const float* Wo    = (const float*)d_in[15];
  const float* bo    = (const float*)d_in[16];
  float* out = (float*)d_out;

  char* ws = (char*)d_ws;
  int* iw      = (int*)ws;
  int* cnt     = iw + 0;
  int* bcur    = iw + 4;
  int* boff    = iw + 8;
  int* off2    = iw + 16;                 // NN*NR+1 = 100001 ints
  int* perm    = iw + 100032;             // 20096 ints
  int* packed  = iw + 120128;             // NE ints (ends 440128)
  int* pos2    = iw + 440640;             // NN ints (ends 460640)
  u64* lb      = (u64*)(iw + 460640);     // NBS u64 lookback slots (8B-aligned)

  size_t fb = 1843456;                    // 460836*4 = 1843344, 256-aligned up
  unsigned char* KVn = (unsigned char*)(ws + fb); fb += 768ull*NPAD;  // 15.43 MB (fp8 K + bf16 V)
  u16*   QA    = (u16*)(ws + fb);   fb += 2ull*NPAD*NR*DD;      // 51.45 MB (perm order)
  u16*   aggrV = (u16*)(ws + fb);   fb += 2ull*NPAD*NR*DD;      // 51.45 MB (perm order)
  u16*   xb    = (u16*)(ws + fb);   fb += 2ull*NN*DD;           // 10.24 MB (dedicated: k_mo residual)
  u16*   Wtk   = (u16*)(ws + fb);   fb += 2ull*3*65536;
  u16*   Wtq   = (u16*)(ws + fb);   fb += 2ull*3*65536;
  u16*   Wtv   = (u16*)(ws + fb);   fb += 2ull*3*65536;
  u16*   Wta   = (u16*)(ws + fb);   fb += 2ull*3*65536;
  u16*   Wot   = (u16*)(ws + fb);   fb += 2ull*NC*DD;
  u16*   Mtm   = (u16*)(ws + fb);   fb += 2ull*NR*NH*KK*KK;
  u16*   Atb   = (u16*)(ws + fb);   fb += 2ull*NR*NH*KK*KK;
  // total ~131 MB (Qn buffer eliminated)

  hipMemsetAsync(iw, 0, (size_t)(16 + NN*NR + 1)*sizeof(int), stream); // cnt,bcur,boff,off2
  hipMemsetAsync(lb, 0, (size_t)NBS*sizeof(u64), stream);              // lookback slots

  k_pre1   <<<1408, 256, 0, stream>>>(ntype, ei, etype, cnt, off2, perm);
  k_scan   <<<NBS+79, 256, 0, stream>>>(off2, lb, cnt, ntype, bcur, perm, pos2, boff);
  k_work1  <<<4854, 256, 0, stream>>>(ei, etype, off2, packed, pos2, x, xb,
                                      Wk, Wq, Wv, Wa, Wtk, Wtq, Wtv, Wta,
                                      rmsg, ratt, prior, Wo, Mtm, Atb, Wot);
  k_projqa <<<1256, 256, 0, stream>>>(xb, perm, boff, Wtk, Wtq, Wtv, bk, bq, bv,
                                      Atb, KVn, QA);
  k_edge   <<<5024, 256, 0, stream>>>(KVn, QA, off2, packed, perm, aggrV);
  k_mo     <<<628, 256, 0, stream>>>(aggrV, Mtm, xb, perm, boff, Wta, ba, Wot, bo, out);
}